// Round 1
// baseline (3521.329 us; speedup 1.0000x reference)
//
#include <hip/hip_runtime.h>

#define N_NODES 16384
#define N_EDGES 262144
#define DIM 512
#define HIDDEN 256
#define TE 64   // edges per workgroup in edge kernel

typedef __attribute__((ext_vector_type(8))) __bf16 bf16x8;
typedef __attribute__((ext_vector_type(4))) __bf16 bf16x4;
typedef __attribute__((ext_vector_type(4))) float f32x4;

__device__ __forceinline__ float silu_f(float x){ return x / (1.f + __expf(-x)); }

__device__ __forceinline__ f32x4 mfma16(bf16x8 a, bf16x8 b, f32x4 c){
  return __builtin_amdgcn_mfma_f32_16x16x32_bf16(a, b, c, 0, 0, 0);
}

// ---------------------------------------------------------------- prep ----
// Rearrange/cast weights to bf16.
//  wab  [1024][512]: o<512 -> We1[o][k] ; o>=512 -> We1[o-512][512+k]
//  weaT [512][64]  : k<51 -> We1[o][1024+k]; k==51 -> We1[o][1075]; else 0
//  we2b/wc1b [512][512], wn1b [256][1024], wn2b [256][256]: straight casts
__global__ void prep_kernel(const float* __restrict__ We1, const float* __restrict__ We2,
                            const float* __restrict__ Wc1, const float* __restrict__ Wn1,
                            const float* __restrict__ Wn2,
                            __bf16* wab, __bf16* weaT, __bf16* we2b, __bf16* wc1b,
                            __bf16* wn1b, __bf16* wn2b){
  int i = blockIdx.x * 256 + threadIdx.x;
  if (i < 1024*512){
    int o = i >> 9, k = i & 511;
    float v = (o < 512) ? We1[(size_t)o*1076 + k] : We1[(size_t)(o-512)*1076 + 512 + k];
    wab[i] = (__bf16)v;
  }
  if (i < 512*64){
    int o = i >> 6, k = i & 63;
    float v = (k < 51) ? We1[(size_t)o*1076 + 1024 + k] : (k == 51 ? We1[(size_t)o*1076 + 1075] : 0.f);
    weaT[i] = (__bf16)v;
  }
  if (i < 512*512){ we2b[i] = (__bf16)We2[i]; wc1b[i] = (__bf16)Wc1[i]; }
  if (i < 256*1024){ wn1b[i] = (__bf16)Wn1[i]; }
  if (i < 256*256){ wn2b[i] = (__bf16)Wn2[i]; }
}

// ------------------------------------------------------------- gemm AB ----
// AB[n][0:512] = h @ We1[:, :512].T ; AB[n][512:1024] = h @ We1[:, 512:1024].T
// A = h (f32, cast on stage), B = wab [1024][512] bf16 (row = out, contiguous K)
__global__ __launch_bounds__(256) void gemm_ab_kernel(const float* __restrict__ h,
                                                      const __bf16* __restrict__ wab,
                                                      __bf16* __restrict__ AB){
  __shared__ __align__(16) __bf16 At[64*512];  // 64KB, swizzled
  int tid = threadIdx.x;
  int r0 = blockIdx.x * 64;
  char* ab = (char*)At;
  for (int it = 0; it < 32; ++it){
    int idx = it*1024 + tid*4;
    int row = idx >> 9, col = idx & 511;
    float4 v = *reinterpret_cast<const float4*>(h + (size_t)(r0+row)*512 + col);
    bf16x4 p = {(__bf16)v.x, (__bf16)v.y, (__bf16)v.z, (__bf16)v.w};
    *reinterpret_cast<bf16x4*>(ab + row*1024 + ((col*2) ^ ((row&7)<<4))) = p;
  }
  __syncthreads();
  int lane = tid & 63, wid = tid >> 6;
  int col16 = lane & 15, g = lane >> 4;
  int arow = wid*16 + col16;
  for (int cc = 0; cc < 8; ++cc){
    f32x4 acc[8];
    #pragma unroll
    for (int t = 0; t < 8; ++t) acc[t] = f32x4{0.f,0.f,0.f,0.f};
    for (int kk = 0; kk < 16; ++kk){
      bf16x8 af = *reinterpret_cast<const bf16x8*>(ab + arow*1024 + ((kk*64 + g*16) ^ ((arow&7)<<4)));
      #pragma unroll
      for (int t = 0; t < 8; ++t){
        int oc = cc*128 + t*16 + col16;
        bf16x8 bf = *reinterpret_cast<const bf16x8*>(wab + (size_t)oc*512 + kk*32 + g*8);
        acc[t] = mfma16(af, bf, acc[t]);
      }
    }
    #pragma unroll
    for (int t = 0; t < 8; ++t){
      int oc = cc*128 + t*16 + col16;
      #pragma unroll
      for (int i2 = 0; i2 < 4; ++i2){
        int row = r0 + wid*16 + g*4 + i2;
        AB[(size_t)row*1024 + oc] = (__bf16)acc[t][i2];
      }
    }
  }
}

// ------------------------------------------------------- fused edge op ----
// Per 64-edge tile: radial, e1 = silu(A[row]+B[col]+ea@Wea + b1),
// e2 = silu(e1@We2 + b2) (-> agg atomics), cu = clip(silu(e2@Wc1+bc1)@wc2),
// pos atomics.
template<int NT>
__device__ __forceinline__ void gemm_tiles_k512(const __bf16* Alds, const __bf16* __restrict__ Bg,
                                                int arow, int g, int col16, f32x4* acc){
  const char* ab = (const char*)Alds;
  for (int kk = 0; kk < 16; ++kk){
    bf16x8 af = *reinterpret_cast<const bf16x8*>(ab + arow*1024 + ((kk*64 + g*16) ^ ((arow&7)<<4)));
    #pragma unroll
    for (int t = 0; t < NT; ++t){
      int oc = t*16 + col16;
      bf16x8 bf = *reinterpret_cast<const bf16x8*>(Bg + (size_t)oc*512 + kk*32 + g*8);
      acc[t] = mfma16(af, bf, acc[t]);
    }
  }
}

__global__ __launch_bounds__(256) void edge_kernel(
    const int* __restrict__ eidx, const float* __restrict__ edge_attr,
    const float* __restrict__ pos,
    const __bf16* __restrict__ AB, const __bf16* __restrict__ weaT,
    const __bf16* __restrict__ we2b, const __bf16* __restrict__ wc1b,
    const float* __restrict__ b1, const float* __restrict__ b2,
    const float* __restrict__ bc1, const float* __restrict__ wc2,
    float* __restrict__ agg, float* __restrict__ pos_out)
{
  __shared__ __align__(16) __bf16 e1t[TE*512];   // 64KB swizzled
  __shared__ __align__(16) __bf16 e2t[TE*512];   // 64KB swizzled
  __shared__ __align__(16) __bf16 eat[TE*64];    // 8KB  swizzled (ea | radial | pad)
  __shared__ float diffs[3][TE];
  __shared__ float rad[TE];
  __shared__ int   rl[TE], cl[TE];
  __shared__ float b1l[512], b2l[512], bc1l[512], wc2l[512];
  __shared__ float cul[TE];

  int tid = threadIdx.x;
  int e0 = blockIdx.x * TE;

  if (tid < TE){
    int e = e0 + tid;
    int r = eidx[e], c = eidx[N_EDGES + e];
    rl[tid] = r; cl[tid] = c;
    float dx = pos[r*3+0]-pos[c*3+0];
    float dy = pos[r*3+1]-pos[c*3+1];
    float dz = pos[r*3+2]-pos[c*3+2];
    diffs[0][tid]=dx; diffs[1][tid]=dy; diffs[2][tid]=dz;
    float rr = dx*dx + dy*dy + dz*dz;
    rad[tid] = fminf(fmaxf(rr, 1e-8f), 100.f);
  }
  for (int i = tid; i < 512; i += 256){ b1l[i]=b1[i]; b2l[i]=b2[i]; bc1l[i]=bc1[i]; wc2l[i]=wc2[i]; }
  __syncthreads();

  // stage edge_attr (+radial at k=51, zeros pad) as swizzled bf16 [TE][64]
  {
    char* eb = (char*)eat;
    for (int i = tid; i < TE*64; i += 256){
      int e = i >> 6, k = i & 63;
      float v = (k < 51) ? edge_attr[(size_t)(e0+e)*51 + k] : (k == 51 ? rad[e] : 0.f);
      *reinterpret_cast<__bf16*>(eb + e*128 + ((k*2) ^ ((e&7)<<4))) = (__bf16)v;
    }
  }
  // prefill e1t with gather-sum + bias (bf16, swizzled)
  {
    int e = tid >> 2, q = tid & 3;
    size_t baseR = (size_t)rl[e]*1024;
    size_t baseC = (size_t)cl[e]*1024 + 512;
    char* eb = (char*)e1t;
    for (int c = 0; c < 16; ++c){
      int o0 = q*8 + c*32;
      bf16x8 ga = *reinterpret_cast<const bf16x8*>(AB + baseR + o0);
      bf16x8 gb = *reinterpret_cast<const bf16x8*>(AB + baseC + o0);
      bf16x8 outv;
      #pragma unroll
      for (int j = 0; j < 8; ++j) outv[j] = (__bf16)((float)ga[j] + (float)gb[j] + b1l[o0+j]);
      *reinterpret_cast<bf16x8*>(eb + e*1024 + ((o0*2) ^ ((e&7)<<4))) = outv;
    }
  }
  __syncthreads();

  int lane = tid & 63, wid = tid >> 6;
  int col16 = lane & 15, g = lane >> 4;
  int r0 = wid * 16;
  int arow = r0 + col16;

  // P0b: e1 += ea@Wea (MFMA, K=64), then silu, back to e1t
  {
    const char* eb = (const char*)eat;
    bf16x8 a0 = *reinterpret_cast<const bf16x8*>(eb + arow*128 + ((g*16)      ^ ((arow&7)<<4)));
    bf16x8 a1 = *reinterpret_cast<const bf16x8*>(eb + arow*128 + ((64 + g*16) ^ ((arow&7)<<4)));
    char* e1b = (char*)e1t;
    #pragma unroll 4
    for (int t = 0; t < 32; ++t){
      int oc = t*16 + col16;
      f32x4 acc;
      #pragma unroll
      for (int i2 = 0; i2 < 4; ++i2){
        int row = r0 + g*4 + i2;
        acc[i2] = (float)*reinterpret_cast<const __bf16*>(e1b + row*1024 + ((oc*2) ^ ((row&7)<<4)));
      }
      bf16x8 bf0 = *reinterpret_cast<const bf16x8*>(weaT + (size_t)oc*64 + g*8);
      bf16x8 bf1 = *reinterpret_cast<const bf16x8*>(weaT + (size_t)oc*64 + 32 + g*8);
      acc = mfma16(a0, bf0, acc);
      acc = mfma16(a1, bf1, acc);
      #pragma unroll
      for (int i2 = 0; i2 < 4; ++i2){
        int row = r0 + g*4 + i2;
        *reinterpret_cast<__bf16*>(e1b + row*1024 + ((oc*2) ^ ((row&7)<<4))) = (__bf16)silu_f(acc[i2]);
      }
    }
  }
  __syncthreads();

  // P1: e2 = silu(e1 @ We2^T + b2); atomics to agg; store e2t
  {
    f32x4 acc[32];
    #pragma unroll
    for (int t = 0; t < 32; ++t) acc[t] = f32x4{0.f,0.f,0.f,0.f};
    gemm_tiles_k512<32>(e1t, we2b, arow, g, col16, acc);
    char* e2b = (char*)e2t;
    #pragma unroll
    for (int t = 0; t < 32; ++t){
      int oc = t*16 + col16;
      #pragma unroll
      for (int i2 = 0; i2 < 4; ++i2){
        int row = r0 + g*4 + i2;
        float v = silu_f(acc[t][i2] + b2l[oc]);
        *reinterpret_cast<__bf16*>(e2b + row*1024 + ((oc*2) ^ ((row&7)<<4))) = (__bf16)v;
        atomicAdd(&agg[(size_t)rl[row]*512 + oc], v);
      }
    }
  }
  __syncthreads();

  // P2: c1 = silu(e2 @ Wc1^T + bc1); cu = c1 . wc2 ; pos atomics
  {
    f32x4 acc[32];
    #pragma unroll
    for (int t = 0; t < 32; ++t) acc[t] = f32x4{0.f,0.f,0.f,0.f};
    gemm_tiles_k512<32>(e2t, wc1b, arow, g, col16, acc);
    float part[4] = {0.f,0.f,0.f,0.f};
    #pragma unroll
    for (int t = 0; t < 32; ++t){
      int oc = t*16 + col16;
      #pragma unroll
      for (int i2 = 0; i2 < 4; ++i2){
        float v = silu_f(acc[t][i2] + bc1l[oc]);
        part[i2] += v * wc2l[oc];
      }
    }
    #pragma unroll
    for (int off = 1; off < 16; off <<= 1){
      #pragma unroll
      for (int i2 = 0; i2 < 4; ++i2) part[i2] += __shfl_xor(part[i2], off, 64);
    }
    if (col16 == 0){
      #pragma unroll
      for (int i2 = 0; i2 < 4; ++i2) cul[r0 + g*4 + i2] = part[i2];
    }
  }
  __syncthreads();

  if (tid < TE){
    float cu0 = cul[tid];
    float cu = fminf(fmaxf(cu0, -1.f), 1.f);
    if (!isfinite(cu0)) cu = 0.f;
    int r = rl[tid];
    atomicAdd(&pos_out[r*3+0], diffs[0][tid]*cu);
    atomicAdd(&pos_out[r*3+1], diffs[1][tid]*cu);
    atomicAdd(&pos_out[r*3+2], diffs[2][tid]*cu);
  }
}

// ------------------------------------------------------------ node MLP ----
__global__ __launch_bounds__(256) void node1_kernel(const float* __restrict__ h,
                                                    const float* __restrict__ agg,
                                                    const __bf16* __restrict__ wn1b,
                                                    const float* __restrict__ bn1,
                                                    __bf16* __restrict__ h1){
  __shared__ __align__(16) __bf16 At[64*1024];  // 128KB, row stride 2048B, swizzled
  int tid = threadIdx.x;
  int r0 = blockIdx.x * 64;
  char* ab = (char*)At;
  for (int it = 0; it < 64; ++it){
    int idx = it*1024 + tid*4;
    int row = idx >> 10, col = idx & 1023;
    float4 v;
    if (col < 512) v = *reinterpret_cast<const float4*>(h   + (size_t)(r0+row)*512 + col);
    else           v = *reinterpret_cast<const float4*>(agg + (size_t)(r0+row)*512 + (col-512));
    bf16x4 p = {(__bf16)v.x, (__bf16)v.y, (__bf16)v.z, (__bf16)v.w};
    *reinterpret_cast<bf16x4*>(ab + row*2048 + ((col*2) ^ ((row&7)<<4))) = p;
  }
  __syncthreads();
  int lane = tid & 63, wid = tid >> 6;
  int col16 = lane & 15, g = lane >> 4;
  int arow = wid*16 + col16;
  f32x4 acc[16];
  #pragma unroll
  for (int t = 0; t < 16; ++t) acc[t] = f32x4{0.f,0.f,0.f,0.f};
  for (int kk = 0; kk < 32; ++kk){
    bf16x8 af = *reinterpret_cast<const bf16x8*>(ab + arow*2048 + ((kk*64 + g*16) ^ ((arow&7)<<4)));
    #pragma unroll
    for (int t = 0; t < 16; ++t){
      int oc = t*16 + col16;
      bf16x8 bf = *reinterpret_cast<const bf16x8*>(wn1b + (size_t)oc*1024 + kk*32 + g*8);
      acc[t] = mfma16(af, bf, acc[t]);
    }
  }
  #pragma unroll
  for (int t = 0; t < 16; ++t){
    int oc = t*16 + col16;
    #pragma unroll
    for (int i2 = 0; i2 < 4; ++i2){
      int row = r0 + wid*16 + g*4 + i2;
      h1[(size_t)row*256 + oc] = (__bf16)silu_f(acc[t][i2] + bn1[oc]);
    }
  }
}

__global__ __launch_bounds__(256) void node2_kernel(const __bf16* __restrict__ h1,
                                                    const __bf16* __restrict__ wn2b,
                                                    const float* __restrict__ bn2,
                                                    float* __restrict__ hout){
  __shared__ __align__(16) __bf16 At[64*256];  // 32KB, row stride 512B, swizzled
  int tid = threadIdx.x;
  int r0 = blockIdx.x * 64;
  char* ab = (char*)At;
  for (int it = 0; it < 8; ++it){
    int idx = it*2048 + tid*8;
    int row = idx >> 8, col = idx & 255;
    bf16x8 v = *reinterpret_cast<const bf16x8*>(h1 + (size_t)(r0+row)*256 + col);
    *reinterpret_cast<bf16x8*>(ab + row*512 + ((col*2) ^ ((row&7)<<4))) = v;
  }
  __syncthreads();
  int lane = tid & 63, wid = tid >> 6;
  int col16 = lane & 15, g = lane >> 4;
  int arow = wid*16 + col16;
  f32x4 acc[16];
  #pragma unroll
  for (int t = 0; t < 16; ++t) acc[t] = f32x4{0.f,0.f,0.f,0.f};
  for (int kk = 0; kk < 8; ++kk){
    bf16x8 af = *reinterpret_cast<const bf16x8*>(ab + arow*512 + ((kk*64 + g*16) ^ ((arow&7)<<4)));
    #pragma unroll
    for (int t = 0; t < 16; ++t){
      int oc = t*16 + col16;
      bf16x8 bf = *reinterpret_cast<const bf16x8*>(wn2b + (size_t)oc*256 + kk*32 + g*8);
      acc[t] = mfma16(af, bf, acc[t]);
    }
  }
  #pragma unroll
  for (int t = 0; t < 16; ++t){
    int oc = t*16 + col16;
    #pragma unroll
    for (int i2 = 0; i2 < 4; ++i2){
      int row = r0 + wid*16 + g*4 + i2;
      hout[(size_t)row*256 + oc] = acc[t][i2] + bn2[oc];
    }
  }
}

// -------------------------------------------------------------- launch ----
extern "C" void kernel_launch(void* const* d_in, const int* in_sizes, int n_in,
                              void* d_out, int out_size, void* d_ws, size_t ws_size,
                              hipStream_t stream){
  const float* h   = (const float*)d_in[0];
  const int*   ei  = (const int*)d_in[1];
  const float* ea  = (const float*)d_in[2];
  const float* pos = (const float*)d_in[3];
  const float* We1 = (const float*)d_in[4];
  const float* be1 = (const float*)d_in[5];
  const float* We2 = (const float*)d_in[6];
  const float* be2 = (const float*)d_in[7];
  const float* Wc1 = (const float*)d_in[8];
  const float* bc1 = (const float*)d_in[9];
  const float* Wc2 = (const float*)d_in[10];
  const float* Wn1 = (const float*)d_in[11];
  const float* bn1 = (const float*)d_in[12];
  const float* Wn2 = (const float*)d_in[13];
  const float* bn2 = (const float*)d_in[14];

  char* ws = (char*)d_ws;
  size_t off = 0;
  auto carve = [&](size_t bytes) -> char* {
    char* p = ws + off; off += (bytes + 255) & ~(size_t)255; return p;
  };
  __bf16* wab  = (__bf16*)carve((size_t)1024*512*2);
  __bf16* weaT = (__bf16*)carve((size_t)512*64*2);
  __bf16* we2b = (__bf16*)carve((size_t)512*512*2);
  __bf16* wc1b = (__bf16*)carve((size_t)512*512*2);
  __bf16* wn1b = (__bf16*)carve((size_t)256*1024*2);
  __bf16* wn2b = (__bf16*)carve((size_t)256*256*2);
  __bf16* AB   = (__bf16*)carve((size_t)N_NODES*1024*2);
  float*  agg  = (float*) carve((size_t)N_NODES*512*4);
  __bf16* h1   = (__bf16*)carve((size_t)N_NODES*256*2);

  float* hout = (float*)d_out;
  float* pout = (float*)d_out + (size_t)N_NODES*256;

  hipMemsetAsync(agg, 0, (size_t)N_NODES*512*4, stream);
  hipMemcpyAsync((void*)pout, (const void*)pos, (size_t)N_NODES*3*4,
                 hipMemcpyDeviceToDevice, stream);

  prep_kernel<<<2048, 256, 0, stream>>>(We1, We2, Wc1, Wn1, Wn2,
                                        wab, weaT, we2b, wc1b, wn1b, wn2b);
  gemm_ab_kernel<<<N_NODES/64, 256, 0, stream>>>(h, wab, AB);
  edge_kernel<<<N_EDGES/TE, 256, 0, stream>>>(ei, ea, pos, AB, weaT, we2b, wc1b,
                                              be1, be2, bc1, Wc2, agg, pout);
  node1_kernel<<<N_NODES/64, 256, 0, stream>>>(h, agg, wn1b, bn1, h1);
  node2_kernel<<<N_NODES/64, 256, 0, stream>>>(h1, wn2b, bn2, hout);
}

// Round 2
// 1229.308 us; speedup vs baseline: 2.8645x; 2.8645x over previous
//
#include <hip/hip_runtime.h>

#define N_NODES 16384
#define N_EDGES 262144
#define DIM 512
#define HIDDEN 256
#define TE 64   // edges per workgroup in edge kernel

typedef __attribute__((ext_vector_type(8))) __bf16 bf16x8;
typedef __attribute__((ext_vector_type(4))) __bf16 bf16x4;
typedef __attribute__((ext_vector_type(4))) float f32x4;

__device__ __forceinline__ float silu_f(float x){ return x / (1.f + __expf(-x)); }

__device__ __forceinline__ f32x4 mfma16(bf16x8 a, bf16x8 b, f32x4 c){
  return __builtin_amdgcn_mfma_f32_16x16x32_bf16(a, b, c, 0, 0, 0);
}

// ---------------------------------------------------------------- prep ----
__global__ void prep_kernel(const float* __restrict__ We1, const float* __restrict__ We2,
                            const float* __restrict__ Wc1, const float* __restrict__ Wn1,
                            const float* __restrict__ Wn2,
                            __bf16* wab, __bf16* weaT, __bf16* we2b, __bf16* wc1b,
                            __bf16* wn1b, __bf16* wn2b){
  int i = blockIdx.x * 256 + threadIdx.x;
  if (i < 1024*512){
    int o = i >> 9, k = i & 511;
    float v = (o < 512) ? We1[(size_t)o*1076 + k] : We1[(size_t)(o-512)*1076 + 512 + k];
    wab[i] = (__bf16)v;
  }
  if (i < 512*64){
    int o = i >> 6, k = i & 63;
    float v = (k < 51) ? We1[(size_t)o*1076 + 1024 + k] : (k == 51 ? We1[(size_t)o*1076 + 1075] : 0.f);
    weaT[i] = (__bf16)v;
  }
  if (i < 512*512){ we2b[i] = (__bf16)We2[i]; wc1b[i] = (__bf16)Wc1[i]; }
  if (i < 256*1024){ wn1b[i] = (__bf16)Wn1[i]; }
  if (i < 256*256){ wn2b[i] = (__bf16)Wn2[i]; }
}

// ------------------------------------------------------------- gemm AB ----
__global__ __launch_bounds__(256) void gemm_ab_kernel(const float* __restrict__ h,
                                                      const __bf16* __restrict__ wab,
                                                      __bf16* __restrict__ AB){
  __shared__ __align__(16) __bf16 At[64*512];  // 64KB, swizzled
  int tid = threadIdx.x;
  int r0 = blockIdx.x * 64;
  char* ab = (char*)At;
  for (int it = 0; it < 32; ++it){
    int idx = it*1024 + tid*4;
    int row = idx >> 9, col = idx & 511;
    float4 v = *reinterpret_cast<const float4*>(h + (size_t)(r0+row)*512 + col);
    bf16x4 p = {(__bf16)v.x, (__bf16)v.y, (__bf16)v.z, (__bf16)v.w};
    *reinterpret_cast<bf16x4*>(ab + row*1024 + ((col*2) ^ ((row&7)<<4))) = p;
  }
  __syncthreads();
  int lane = tid & 63, wid = tid >> 6;
  int col16 = lane & 15, g = lane >> 4;
  int arow = wid*16 + col16;
  for (int cc = 0; cc < 8; ++cc){
    f32x4 acc[8];
    #pragma unroll
    for (int t = 0; t < 8; ++t) acc[t] = f32x4{0.f,0.f,0.f,0.f};
    for (int kk = 0; kk < 16; ++kk){
      bf16x8 af = *reinterpret_cast<const bf16x8*>(ab + arow*1024 + ((kk*64 + g*16) ^ ((arow&7)<<4)));
      #pragma unroll
      for (int t = 0; t < 8; ++t){
        int oc = cc*128 + t*16 + col16;
        bf16x8 bf = *reinterpret_cast<const bf16x8*>(wab + (size_t)oc*512 + kk*32 + g*8);
        acc[t] = mfma16(af, bf, acc[t]);
      }
    }
    #pragma unroll
    for (int t = 0; t < 8; ++t){
      int oc = cc*128 + t*16 + col16;
      #pragma unroll
      for (int i2 = 0; i2 < 4; ++i2){
        int row = r0 + wid*16 + g*4 + i2;
        AB[(size_t)row*1024 + oc] = (__bf16)acc[t][i2];
      }
    }
  }
}

// ------------------------------------------------------- fused edge op ----
// Col-split K=512 GEMM: wave `wid` computes all 64 edge-rows x its own
// 128-col strip. B-fragments register-double-buffered one full kk ahead so
// ~32 MFMAs (160cy) cover L2 latency of the 8 prefetch loads.
__device__ __forceinline__ void gemm_colsplit(const __bf16* Alds, const __bf16* __restrict__ Bg,
                                              int wid, int lane, f32x4 acc[4][8]){
  const char* ab = (const char*)Alds;
  int col16 = lane & 15, g = lane >> 4;
  const __bf16* Brow = Bg + (size_t)(wid*128 + col16)*512 + g*8;
  bf16x8 bcur[8], bnxt[8];
  #pragma unroll
  for (int ct = 0; ct < 8; ++ct) bcur[ct] = *reinterpret_cast<const bf16x8*>(Brow + ct*8192);
  for (int kk = 0; kk < 16; ++kk){
    if (kk < 15){
      #pragma unroll
      for (int ct = 0; ct < 8; ++ct)
        bnxt[ct] = *reinterpret_cast<const bf16x8*>(Brow + (kk+1)*32 + ct*8192);
    }
    #pragma unroll
    for (int rt = 0; rt < 4; ++rt){
      int arow = rt*16 + col16;
      bf16x8 af = *reinterpret_cast<const bf16x8*>(ab + arow*1024 + ((kk*64 + g*16) ^ ((arow&7)<<4)));
      #pragma unroll
      for (int ct = 0; ct < 8; ++ct)
        acc[rt][ct] = mfma16(af, bcur[ct], acc[rt][ct]);
    }
    #pragma unroll
    for (int ct = 0; ct < 8; ++ct) bcur[ct] = bnxt[ct];
  }
}

__global__ __launch_bounds__(256, 2) void edge_kernel(
    const int* __restrict__ eidx, const float* __restrict__ edge_attr,
    const float* __restrict__ pos,
    const __bf16* __restrict__ AB, const __bf16* __restrict__ weaT,
    const __bf16* __restrict__ we2b, const __bf16* __restrict__ wc1b,
    const float* __restrict__ b1, const float* __restrict__ b2,
    const float* __restrict__ bc1, const float* __restrict__ wc2,
    float* __restrict__ agg, float* __restrict__ pos_out)
{
  __shared__ __align__(16) __bf16 e1t[TE*512];   // 64KB swizzled (e1, later e2)
  __shared__ __align__(16) __bf16 eat[TE*64];    // 8KB  swizzled (ea | radial | pad)
  __shared__ float diffs[3][TE];
  __shared__ float rad[TE];
  __shared__ int   rl[TE], cl[TE];
  __shared__ float b1l[512];
  __shared__ float cupart[4][TE];

  int tid = threadIdx.x;
  int e0 = blockIdx.x * TE;

  if (tid < TE){
    int e = e0 + tid;
    int r = eidx[e], c = eidx[N_EDGES + e];
    rl[tid] = r; cl[tid] = c;
    float dx = pos[r*3+0]-pos[c*3+0];
    float dy = pos[r*3+1]-pos[c*3+1];
    float dz = pos[r*3+2]-pos[c*3+2];
    diffs[0][tid]=dx; diffs[1][tid]=dy; diffs[2][tid]=dz;
    float rr = dx*dx + dy*dy + dz*dz;
    rad[tid] = fminf(fmaxf(rr, 1e-8f), 100.f);
  }
  for (int i = tid; i < 512; i += 256) b1l[i] = b1[i];
  __syncthreads();

  // stage edge_attr (+radial at k=51, zero pad) as swizzled bf16 [TE][64]
  {
    char* eb = (char*)eat;
    for (int i = tid; i < TE*64; i += 256){
      int e = i >> 6, k = i & 63;
      float v = (k < 51) ? edge_attr[(size_t)(e0+e)*51 + k] : (k == 51 ? rad[e] : 0.f);
      *reinterpret_cast<__bf16*>(eb + e*128 + ((k*2) ^ ((e&7)<<4))) = (__bf16)v;
    }
  }
  // prefill e1t with gather-sum + bias (bf16, swizzled)
  {
    int e = tid >> 2, q = tid & 3;
    size_t baseR = (size_t)rl[e]*1024;
    size_t baseC = (size_t)cl[e]*1024 + 512;
    char* eb = (char*)e1t;
    for (int c = 0; c < 16; ++c){
      int o0 = q*8 + c*32;
      bf16x8 ga = *reinterpret_cast<const bf16x8*>(AB + baseR + o0);
      bf16x8 gb = *reinterpret_cast<const bf16x8*>(AB + baseC + o0);
      bf16x8 outv;
      #pragma unroll
      for (int j = 0; j < 8; ++j) outv[j] = (__bf16)((float)ga[j] + (float)gb[j] + b1l[o0+j]);
      *reinterpret_cast<bf16x8*>(eb + e*1024 + ((o0*2) ^ ((e&7)<<4))) = outv;
    }
  }
  __syncthreads();

  int lane = tid & 63, wid = tid >> 6;
  int col16 = lane & 15, g = lane >> 4;
  int r0 = wid * 16;
  int arow0 = r0 + col16;

  // P0b: e1 += ea@Wea (MFMA, K=64), then silu, back to e1t (row-split)
  {
    const char* eb = (const char*)eat;
    bf16x8 a0 = *reinterpret_cast<const bf16x8*>(eb + arow0*128 + ((g*16)      ^ ((arow0&7)<<4)));
    bf16x8 a1 = *reinterpret_cast<const bf16x8*>(eb + arow0*128 + ((64 + g*16) ^ ((arow0&7)<<4)));
    char* e1b = (char*)e1t;
    #pragma unroll 4
    for (int t = 0; t < 32; ++t){
      int oc = t*16 + col16;
      f32x4 acc;
      #pragma unroll
      for (int i2 = 0; i2 < 4; ++i2){
        int row = r0 + g*4 + i2;
        acc[i2] = (float)*reinterpret_cast<const __bf16*>(e1b + row*1024 + ((oc*2) ^ ((row&7)<<4)));
      }
      bf16x8 bf0 = *reinterpret_cast<const bf16x8*>(weaT + (size_t)oc*64 + g*8);
      bf16x8 bf1 = *reinterpret_cast<const bf16x8*>(weaT + (size_t)oc*64 + 32 + g*8);
      acc = mfma16(a0, bf0, acc);
      acc = mfma16(a1, bf1, acc);
      #pragma unroll
      for (int i2 = 0; i2 < 4; ++i2){
        int row = r0 + g*4 + i2;
        *reinterpret_cast<__bf16*>(e1b + row*1024 + ((oc*2) ^ ((row&7)<<4))) = (__bf16)silu_f(acc[i2]);
      }
    }
  }
  __syncthreads();

  // P1: e2 = silu(e1 @ We2^T + b2); write e2 back into e1t; atomics to agg
  {
    f32x4 acc[4][8];
    #pragma unroll
    for (int rt = 0; rt < 4; ++rt)
      #pragma unroll
      for (int ct = 0; ct < 8; ++ct) acc[rt][ct] = f32x4{0.f,0.f,0.f,0.f};
    gemm_colsplit(e1t, we2b, wid, lane, acc);
    __syncthreads();   // everyone done READING e1t
    char* e1b = (char*)e1t;
    #pragma unroll
    for (int ct = 0; ct < 8; ++ct){
      int oc = wid*128 + ct*16 + col16;
      float b2v = b2[oc];
      #pragma unroll
      for (int rt = 0; rt < 4; ++rt){
        #pragma unroll
        for (int i2 = 0; i2 < 4; ++i2){
          int row = rt*16 + g*4 + i2;
          float v = silu_f(acc[rt][ct][i2] + b2v);
          *reinterpret_cast<__bf16*>(e1b + row*1024 + ((oc*2) ^ ((row&7)<<4))) = (__bf16)v;
          atomicAdd(&agg[(size_t)rl[row]*512 + oc], v);
        }
      }
    }
  }
  __syncthreads();

  // P2: c1 = silu(e2 @ Wc1^T + bc1); cu = c1 . wc2 ; pos atomics
  {
    f32x4 acc[4][8];
    #pragma unroll
    for (int rt = 0; rt < 4; ++rt)
      #pragma unroll
      for (int ct = 0; ct < 8; ++ct) acc[rt][ct] = f32x4{0.f,0.f,0.f,0.f};
    gemm_colsplit(e1t, wc1b, wid, lane, acc);
    float part[4][4];
    #pragma unroll
    for (int rt = 0; rt < 4; ++rt)
      #pragma unroll
      for (int i2 = 0; i2 < 4; ++i2) part[rt][i2] = 0.f;
    #pragma unroll
    for (int ct = 0; ct < 8; ++ct){
      int oc = wid*128 + ct*16 + col16;
      float bcv = bc1[oc], wcv = wc2[oc];
      #pragma unroll
      for (int rt = 0; rt < 4; ++rt)
        #pragma unroll
        for (int i2 = 0; i2 < 4; ++i2)
          part[rt][i2] += silu_f(acc[rt][ct][i2] + bcv) * wcv;
    }
    #pragma unroll
    for (int off = 1; off < 16; off <<= 1){
      #pragma unroll
      for (int rt = 0; rt < 4; ++rt)
        #pragma unroll
        for (int i2 = 0; i2 < 4; ++i2) part[rt][i2] += __shfl_xor(part[rt][i2], off, 64);
    }
    if (col16 == 0){
      #pragma unroll
      for (int rt = 0; rt < 4; ++rt)
        #pragma unroll
        for (int i2 = 0; i2 < 4; ++i2) cupart[wid][rt*16 + g*4 + i2] = part[rt][i2];
    }
  }
  __syncthreads();

  if (tid < TE){
    float cu0 = cupart[0][tid] + cupart[1][tid] + cupart[2][tid] + cupart[3][tid];
    float cu = fminf(fmaxf(cu0, -1.f), 1.f);
    if (!isfinite(cu0)) cu = 0.f;
    int r = rl[tid];
    atomicAdd(&pos_out[r*3+0], diffs[0][tid]*cu);
    atomicAdd(&pos_out[r*3+1], diffs[1][tid]*cu);
    atomicAdd(&pos_out[r*3+2], diffs[2][tid]*cu);
  }
}

// ------------------------------------------------------------ node MLP ----
__global__ __launch_bounds__(256) void node1_kernel(const float* __restrict__ h,
                                                    const float* __restrict__ agg,
                                                    const __bf16* __restrict__ wn1b,
                                                    const float* __restrict__ bn1,
                                                    __bf16* __restrict__ h1){
  __shared__ __align__(16) __bf16 At[64*1024];  // 128KB, row stride 2048B, swizzled
  int tid = threadIdx.x;
  int r0 = blockIdx.x * 64;
  char* ab = (char*)At;
  for (int it = 0; it < 64; ++it){
    int idx = it*1024 + tid*4;
    int row = idx >> 10, col = idx & 1023;
    float4 v;
    if (col < 512) v = *reinterpret_cast<const float4*>(h   + (size_t)(r0+row)*512 + col);
    else           v = *reinterpret_cast<const float4*>(agg + (size_t)(r0+row)*512 + (col-512));
    bf16x4 p = {(__bf16)v.x, (__bf16)v.y, (__bf16)v.z, (__bf16)v.w};
    *reinterpret_cast<bf16x4*>(ab + row*2048 + ((col*2) ^ ((row&7)<<4))) = p;
  }
  __syncthreads();
  int lane = tid & 63, wid = tid >> 6;
  int col16 = lane & 15, g = lane >> 4;
  int arow = wid*16 + col16;
  f32x4 acc[16];
  #pragma unroll
  for (int t = 0; t < 16; ++t) acc[t] = f32x4{0.f,0.f,0.f,0.f};
  for (int kk = 0; kk < 32; ++kk){
    bf16x8 af = *reinterpret_cast<const bf16x8*>(ab + arow*2048 + ((kk*64 + g*16) ^ ((arow&7)<<4)));
    #pragma unroll
    for (int t = 0; t < 16; ++t){
      int oc = t*16 + col16;
      bf16x8 bf = *reinterpret_cast<const bf16x8*>(wn1b + (size_t)oc*1024 + kk*32 + g*8);
      acc[t] = mfma16(af, bf, acc[t]);
    }
  }
  #pragma unroll
  for (int t = 0; t < 16; ++t){
    int oc = t*16 + col16;
    #pragma unroll
    for (int i2 = 0; i2 < 4; ++i2){
      int row = r0 + wid*16 + g*4 + i2;
      h1[(size_t)row*256 + oc] = (__bf16)silu_f(acc[t][i2] + bn1[oc]);
    }
  }
}

__global__ __launch_bounds__(256) void node2_kernel(const __bf16* __restrict__ h1,
                                                    const __bf16* __restrict__ wn2b,
                                                    const float* __restrict__ bn2,
                                                    float* __restrict__ hout){
  __shared__ __align__(16) __bf16 At[64*256];  // 32KB, row stride 512B, swizzled
  int tid = threadIdx.x;
  int r0 = blockIdx.x * 64;
  char* ab = (char*)At;
  for (int it = 0; it < 8; ++it){
    int idx = it*2048 + tid*8;
    int row = idx >> 8, col = idx & 255;
    bf16x8 v = *reinterpret_cast<const bf16x8*>(h1 + (size_t)(r0+row)*256 + col);
    *reinterpret_cast<bf16x8*>(ab + row*512 + ((col*2) ^ ((row&7)<<4))) = v;
  }
  __syncthreads();
  int lane = tid & 63, wid = tid >> 6;
  int col16 = lane & 15, g = lane >> 4;
  int arow = wid*16 + col16;
  f32x4 acc[16];
  #pragma unroll
  for (int t = 0; t < 16; ++t) acc[t] = f32x4{0.f,0.f,0.f,0.f};
  for (int kk = 0; kk < 8; ++kk){
    bf16x8 af = *reinterpret_cast<const bf16x8*>(ab + arow*512 + ((kk*64 + g*16) ^ ((arow&7)<<4)));
    #pragma unroll
    for (int t = 0; t < 16; ++t){
      int oc = t*16 + col16;
      bf16x8 bf = *reinterpret_cast<const bf16x8*>(wn2b + (size_t)oc*256 + kk*32 + g*8);
      acc[t] = mfma16(af, bf, acc[t]);
    }
  }
  #pragma unroll
  for (int t = 0; t < 16; ++t){
    int oc = t*16 + col16;
    #pragma unroll
    for (int i2 = 0; i2 < 4; ++i2){
      int row = r0 + wid*16 + g*4 + i2;
      hout[(size_t)row*256 + oc] = acc[t][i2] + bn2[oc];
    }
  }
}

// -------------------------------------------------------------- launch ----
extern "C" void kernel_launch(void* const* d_in, const int* in_sizes, int n_in,
                              void* d_out, int out_size, void* d_ws, size_t ws_size,
                              hipStream_t stream){
  const float* h   = (const float*)d_in[0];
  const int*   ei  = (const int*)d_in[1];
  const float* ea  = (const float*)d_in[2];
  const float* pos = (const float*)d_in[3];
  const float* We1 = (const float*)d_in[4];
  const float* be1 = (const float*)d_in[5];
  const float* We2 = (const float*)d_in[6];
  const float* be2 = (const float*)d_in[7];
  const float* Wc1 = (const float*)d_in[8];
  const float* bc1 = (const float*)d_in[9];
  const float* Wc2 = (const float*)d_in[10];
  const float* Wn1 = (const float*)d_in[11];
  const float* bn1 = (const float*)d_in[12];
  const float* Wn2 = (const float*)d_in[13];
  const float* bn2 = (const float*)d_in[14];

  char* ws = (char*)d_ws;
  size_t off = 0;
  auto carve = [&](size_t bytes) -> char* {
    char* p = ws + off; off += (bytes + 255) & ~(size_t)255; return p;
  };
  __bf16* wab  = (__bf16*)carve((size_t)1024*512*2);
  __bf16* weaT = (__bf16*)carve((size_t)512*64*2);
  __bf16* we2b = (__bf16*)carve((size_t)512*512*2);
  __bf16* wc1b = (__bf16*)carve((size_t)512*512*2);
  __bf16* wn1b = (__bf16*)carve((size_t)256*1024*2);
  __bf16* wn2b = (__bf16*)carve((size_t)256*256*2);
  __bf16* AB   = (__bf16*)carve((size_t)N_NODES*1024*2);
  float*  agg  = (float*) carve((size_t)N_NODES*512*4);
  __bf16* h1   = (__bf16*)carve((size_t)N_NODES*256*2);

  float* hout = (float*)d_out;
  float* pout = (float*)d_out + (size_t)N_NODES*256;

  hipMemsetAsync(agg, 0, (size_t)N_NODES*512*4, stream);
  hipMemcpyAsync((void*)pout, (const void*)pos, (size_t)N_NODES*3*4,
                 hipMemcpyDeviceToDevice, stream);

  prep_kernel<<<2048, 256, 0, stream>>>(We1, We2, Wc1, Wn1, Wn2,
                                        wab, weaT, we2b, wc1b, wn1b, wn2b);
  gemm_ab_kernel<<<N_NODES/64, 256, 0, stream>>>(h, wab, AB);
  edge_kernel<<<N_EDGES/TE, 256, 0, stream>>>(ei, ea, pos, AB, weaT, we2b, wc1b,
                                              be1, be2, bc1, Wc2, agg, pout);
  node1_kernel<<<N_NODES/64, 256, 0, stream>>>(h, agg, wn1b, bn1, h1);
  node2_kernel<<<N_NODES/64, 256, 0, stream>>>(h1, wn2b, bn2, hout);
}

// Round 3
// 1208.195 us; speedup vs baseline: 2.9145x; 1.0175x over previous
//
#include <hip/hip_runtime.h>

#define N_NODES 16384
#define N_EDGES 262144
#define TE 64   // edges per workgroup in edge kernel

typedef __attribute__((ext_vector_type(8))) __bf16 bf16x8;
typedef __attribute__((ext_vector_type(4))) __bf16 bf16x4;
typedef __attribute__((ext_vector_type(4))) float f32x4;
typedef __attribute__((ext_vector_type(16))) float f32x16;

__device__ __forceinline__ float silu_f(float x){ return x / (1.f + __expf(-x)); }

__device__ __forceinline__ f32x4 mfma16(bf16x8 a, bf16x8 b, f32x4 c){
  return __builtin_amdgcn_mfma_f32_16x16x32_bf16(a, b, c, 0, 0, 0);
}
__device__ __forceinline__ f32x16 mfma32(bf16x8 a, bf16x8 b, f32x16 c){
  return __builtin_amdgcn_mfma_f32_32x32x16_bf16(a, b, c, 0, 0, 0);
}

// ---------------------------------------------------------------- prep ----
// weaT [512][64]: k<51 -> We1[o][1024+k]; k==51 -> We1[o][1075] (radial col);
//                 k==52 -> b1[o] (bias via constant-1 input); else 0
__global__ void prep_kernel(const float* __restrict__ We1, const float* __restrict__ be1,
                            const float* __restrict__ We2,
                            const float* __restrict__ Wc1, const float* __restrict__ Wn1,
                            const float* __restrict__ Wn2,
                            __bf16* wab, __bf16* weaT, __bf16* we2b, __bf16* wc1b,
                            __bf16* wn1b, __bf16* wn2b){
  int i = blockIdx.x * 256 + threadIdx.x;
  if (i < 1024*512){
    int o = i >> 9, k = i & 511;
    float v = (o < 512) ? We1[(size_t)o*1076 + k] : We1[(size_t)(o-512)*1076 + 512 + k];
    wab[i] = (__bf16)v;
  }
  if (i < 512*64){
    int o = i >> 6, k = i & 63;
    float v = (k < 51) ? We1[(size_t)o*1076 + 1024 + k]
            : (k == 51 ? We1[(size_t)o*1076 + 1075]
            : (k == 52 ? be1[o] : 0.f));
    weaT[i] = (__bf16)v;
  }
  if (i < 512*512){ we2b[i] = (__bf16)We2[i]; wc1b[i] = (__bf16)Wc1[i]; }
  if (i < 256*1024){ wn1b[i] = (__bf16)Wn1[i]; }
  if (i < 256*256){ wn2b[i] = (__bf16)Wn2[i]; }
}

// ------------------------------------------------------------- gemm AB ----
__global__ __launch_bounds__(256) void gemm_ab_kernel(const float* __restrict__ h,
                                                      const __bf16* __restrict__ wab,
                                                      __bf16* __restrict__ AB){
  __shared__ __align__(16) __bf16 At[64*512];  // 64KB, swizzled
  int tid = threadIdx.x;
  int r0 = blockIdx.x * 64;
  char* ab = (char*)At;
  for (int it = 0; it < 32; ++it){
    int idx = it*1024 + tid*4;
    int row = idx >> 9, col = idx & 511;
    float4 v = *reinterpret_cast<const float4*>(h + (size_t)(r0+row)*512 + col);
    bf16x4 p = {(__bf16)v.x, (__bf16)v.y, (__bf16)v.z, (__bf16)v.w};
    *reinterpret_cast<bf16x4*>(ab + row*1024 + ((col*2) ^ ((row&7)<<4))) = p;
  }
  __syncthreads();
  int lane = tid & 63, wid = tid >> 6;
  int col16 = lane & 15, g = lane >> 4;
  int arow = wid*16 + col16;
  for (int cc = 0; cc < 8; ++cc){
    f32x4 acc[8];
    #pragma unroll
    for (int t = 0; t < 8; ++t) acc[t] = f32x4{0.f,0.f,0.f,0.f};
    for (int kk = 0; kk < 16; ++kk){
      bf16x8 af = *reinterpret_cast<const bf16x8*>(ab + arow*1024 + ((kk*64 + g*16) ^ ((arow&7)<<4)));
      #pragma unroll
      for (int t = 0; t < 8; ++t){
        int oc = cc*128 + t*16 + col16;
        bf16x8 bfr = *reinterpret_cast<const bf16x8*>(wab + (size_t)oc*512 + kk*32 + g*8);
        acc[t] = mfma16(af, bfr, acc[t]);
      }
    }
    #pragma unroll
    for (int t = 0; t < 8; ++t){
      int oc = cc*128 + t*16 + col16;
      #pragma unroll
      for (int i2 = 0; i2 < 4; ++i2){
        int row = r0 + wid*16 + g*4 + i2;
        AB[(size_t)row*1024 + oc] = (__bf16)acc[t][i2];
      }
    }
  }
}

// ------------------------------------------------------- fused edge op ----
// 512 threads = 8 waves; wave `wid` owns a 64-col strip (2 tiles of 32) for
// all 64 edges (2 row-tiles of 32). 32x32x16 MFMA. 2 wg/CU -> 16 waves/CU.
__global__ __launch_bounds__(512, 4) void edge_kernel(
    const int* __restrict__ eidx, const float* __restrict__ edge_attr,
    const float* __restrict__ pos,
    const __bf16* __restrict__ AB, const __bf16* __restrict__ weaT,
    const __bf16* __restrict__ we2b, const __bf16* __restrict__ wc1b,
    const float* __restrict__ b2,
    const float* __restrict__ bc1, const float* __restrict__ wc2,
    float* __restrict__ agg, float* __restrict__ pos_out)
{
  __shared__ __align__(16) __bf16 e1t[TE*512];   // 64KB swizzled (e1, later e2)
  __shared__ __align__(16) __bf16 eat[TE*64];    // 8KB  swizzled (ea|radial|1|pad)
  __shared__ float diffs[3][TE];
  __shared__ float rad[TE];
  __shared__ int   rl[TE], cl[TE];
  __shared__ float cupart[8][TE];

  int tid = threadIdx.x;
  int e0 = blockIdx.x * TE;

  if (tid < TE){
    int e = e0 + tid;
    int r = eidx[e], c = eidx[N_EDGES + e];
    rl[tid] = r; cl[tid] = c;
    float dx = pos[r*3+0]-pos[c*3+0];
    float dy = pos[r*3+1]-pos[c*3+1];
    float dz = pos[r*3+2]-pos[c*3+2];
    diffs[0][tid]=dx; diffs[1][tid]=dy; diffs[2][tid]=dz;
    float rr = dx*dx + dy*dy + dz*dz;
    rad[tid] = fminf(fmaxf(rr, 1e-8f), 100.f);
  }
  __syncthreads();

  // stage edge_attr (+radial k=51, one k=52, zero pad) swizzled bf16 [TE][64]
  {
    char* eb = (char*)eat;
    for (int i = tid; i < TE*64; i += 512){
      int e = i >> 6, k = i & 63;
      float v = (k < 51) ? edge_attr[(size_t)(e0+e)*51 + k]
              : (k == 51 ? rad[e] : (k == 52 ? 1.0f : 0.f));
      *reinterpret_cast<__bf16*>(eb + e*128 + ((k*2) ^ ((e&7)<<4))) = (__bf16)v;
    }
  }
  // prefill e1t with gather-sum (bf16, swizzled); bias comes via weaT k=52
  {
    int e = tid >> 3, q = tid & 7;
    size_t baseR = (size_t)rl[e]*1024;
    size_t baseC = (size_t)cl[e]*1024 + 512;
    char* eb = (char*)e1t;
    #pragma unroll
    for (int c = 0; c < 8; ++c){
      int o0 = q*8 + c*64;
      bf16x8 ga = *reinterpret_cast<const bf16x8*>(AB + baseR + o0);
      bf16x8 gb = *reinterpret_cast<const bf16x8*>(AB + baseC + o0);
      bf16x8 outv;
      #pragma unroll
      for (int j = 0; j < 8; ++j) outv[j] = (__bf16)((float)ga[j] + (float)gb[j]);
      *reinterpret_cast<bf16x8*>(eb + e*1024 + ((o0*2) ^ ((e&7)<<4))) = outv;
    }
  }
  __syncthreads();

  int lane = tid & 63, wid = tid >> 6;
  int c31 = lane & 31, hi = lane >> 5;
  int colbase = wid * 64;
  char* e1b = (char*)e1t;

  // P0: e1 = silu(prefill + ea@Wea^T)  (K=64, bias folded at k=52)
  {
    f32x16 acc[2][2];
    #pragma unroll
    for (int rt = 0; rt < 2; ++rt)
      #pragma unroll
      for (int ct = 0; ct < 2; ++ct)
        #pragma unroll
        for (int r = 0; r < 16; ++r) acc[rt][ct][r] = 0.f;
    const char* eb = (const char*)eat;
    #pragma unroll
    for (int kk = 0; kk < 4; ++kk){
      bf16x8 af[2];
      #pragma unroll
      for (int rt = 0; rt < 2; ++rt){
        int arow = rt*32 + c31;
        af[rt] = *reinterpret_cast<const bf16x8*>(eb + arow*128 + ((kk*32 + hi*16) ^ ((arow&7)<<4)));
      }
      #pragma unroll
      for (int ct = 0; ct < 2; ++ct){
        int oc = colbase + ct*32 + c31;
        bf16x8 bfr = *reinterpret_cast<const bf16x8*>(weaT + (size_t)oc*64 + kk*16 + hi*8);
        #pragma unroll
        for (int rt = 0; rt < 2; ++rt) acc[rt][ct] = mfma32(af[rt], bfr, acc[rt][ct]);
      }
    }
    #pragma unroll
    for (int rt = 0; rt < 2; ++rt){
      #pragma unroll
      for (int reg = 0; reg < 16; ++reg){
        int row = rt*32 + (reg&3) + 8*(reg>>2) + 4*hi;
        #pragma unroll
        for (int ct = 0; ct < 2; ++ct){
          int oc = colbase + ct*32 + c31;
          __bf16* p = reinterpret_cast<__bf16*>(e1b + row*1024 + ((oc*2) ^ ((row&7)<<4)));
          float v = (float)*p + acc[rt][ct][reg];
          *p = (__bf16)silu_f(v);
        }
      }
    }
  }
  __syncthreads();

  // P1: e2 = silu(e1 @ We2^T + b2); e2 -> e1t; atomics to agg
  {
    f32x16 acc[2][2];
    #pragma unroll
    for (int rt = 0; rt < 2; ++rt)
      #pragma unroll
      for (int ct = 0; ct < 2; ++ct)
        #pragma unroll
        for (int r = 0; r < 16; ++r) acc[rt][ct][r] = 0.f;
    const __bf16* Brow = we2b + (size_t)(colbase + c31)*512 + hi*8;
    bf16x8 bcur[2], bnxt[2];
    #pragma unroll
    for (int ct = 0; ct < 2; ++ct) bcur[ct] = *reinterpret_cast<const bf16x8*>(Brow + ct*16384);
    for (int kk = 0; kk < 32; ++kk){
      if (kk < 31){
        #pragma unroll
        for (int ct = 0; ct < 2; ++ct)
          bnxt[ct] = *reinterpret_cast<const bf16x8*>(Brow + (kk+1)*16 + ct*16384);
      }
      bf16x8 af[2];
      #pragma unroll
      for (int rt = 0; rt < 2; ++rt){
        int arow = rt*32 + c31;
        af[rt] = *reinterpret_cast<const bf16x8*>(e1b + arow*1024 + ((kk*32 + hi*16) ^ ((arow&7)<<4)));
      }
      #pragma unroll
      for (int ct = 0; ct < 2; ++ct)
        #pragma unroll
        for (int rt = 0; rt < 2; ++rt)
          acc[rt][ct] = mfma32(af[rt], bcur[ct], acc[rt][ct]);
      #pragma unroll
      for (int ct = 0; ct < 2; ++ct) bcur[ct] = bnxt[ct];
    }
    __syncthreads();   // all waves done READING e1t
    float b2v[2];
    #pragma unroll
    for (int ct = 0; ct < 2; ++ct) b2v[ct] = b2[colbase + ct*32 + c31];
    #pragma unroll
    for (int rt = 0; rt < 2; ++rt){
      #pragma unroll
      for (int reg = 0; reg < 16; ++reg){
        int row = rt*32 + (reg&3) + 8*(reg>>2) + 4*hi;
        int node = rl[row];
        #pragma unroll
        for (int ct = 0; ct < 2; ++ct){
          int oc = colbase + ct*32 + c31;
          float v = silu_f(acc[rt][ct][reg] + b2v[ct]);
          *reinterpret_cast<__bf16*>(e1b + row*1024 + ((oc*2) ^ ((row&7)<<4))) = (__bf16)v;
          atomicAdd(&agg[(size_t)node*512 + oc], v);
        }
      }
    }
  }
  __syncthreads();

  // P2: c1 = silu(e2 @ Wc1^T + bc1); cu partial = c1 . wc2
  {
    f32x16 acc[2][2];
    #pragma unroll
    for (int rt = 0; rt < 2; ++rt)
      #pragma unroll
      for (int ct = 0; ct < 2; ++ct)
        #pragma unroll
        for (int r = 0; r < 16; ++r) acc[rt][ct][r] = 0.f;
    const __bf16* Brow = wc1b + (size_t)(colbase + c31)*512 + hi*8;
    bf16x8 bcur[2], bnxt[2];
    #pragma unroll
    for (int ct = 0; ct < 2; ++ct) bcur[ct] = *reinterpret_cast<const bf16x8*>(Brow + ct*16384);
    for (int kk = 0; kk < 32; ++kk){
      if (kk < 31){
        #pragma unroll
        for (int ct = 0; ct < 2; ++ct)
          bnxt[ct] = *reinterpret_cast<const bf16x8*>(Brow + (kk+1)*16 + ct*16384);
      }
      bf16x8 af[2];
      #pragma unroll
      for (int rt = 0; rt < 2; ++rt){
        int arow = rt*32 + c31;
        af[rt] = *reinterpret_cast<const bf16x8*>(e1b + arow*1024 + ((kk*32 + hi*16) ^ ((arow&7)<<4)));
      }
      #pragma unroll
      for (int ct = 0; ct < 2; ++ct)
        #pragma unroll
        for (int rt = 0; rt < 2; ++rt)
          acc[rt][ct] = mfma32(af[rt], bcur[ct], acc[rt][ct]);
      #pragma unroll
      for (int ct = 0; ct < 2; ++ct) bcur[ct] = bnxt[ct];
    }
    float bcv[2], wcv[2];
    #pragma unroll
    for (int ct = 0; ct < 2; ++ct){
      int oc = colbase + ct*32 + c31;
      bcv[ct] = bc1[oc]; wcv[ct] = wc2[oc];
    }
    #pragma unroll
    for (int rt = 0; rt < 2; ++rt){
      #pragma unroll
      for (int reg = 0; reg < 16; ++reg){
        float pv = 0.f;
        #pragma unroll
        for (int ct = 0; ct < 2; ++ct)
          pv += silu_f(acc[rt][ct][reg] + bcv[ct]) * wcv[ct];
        #pragma unroll
        for (int off = 1; off < 32; off <<= 1) pv += __shfl_xor(pv, off, 64);
        if (c31 == 0){
          int row = rt*32 + (reg&3) + 8*(reg>>2) + 4*hi;
          cupart[wid][row] = pv;
        }
      }
    }
  }
  __syncthreads();

  if (tid < TE){
    float cu0 = 0.f;
    #pragma unroll
    for (int w = 0; w < 8; ++w) cu0 += cupart[w][tid];
    float cu = fminf(fmaxf(cu0, -1.f), 1.f);
    if (!isfinite(cu0)) cu = 0.f;
    int r = rl[tid];
    atomicAdd(&pos_out[r*3+0], diffs[0][tid]*cu);
    atomicAdd(&pos_out[r*3+1], diffs[1][tid]*cu);
    atomicAdd(&pos_out[r*3+2], diffs[2][tid]*cu);
  }
}

// ------------------------------------------------------------ node MLP ----
__global__ __launch_bounds__(256) void node1_kernel(const float* __restrict__ h,
                                                    const float* __restrict__ agg,
                                                    const __bf16* __restrict__ wn1b,
                                                    const float* __restrict__ bn1,
                                                    __bf16* __restrict__ h1){
  __shared__ __align__(16) __bf16 At[64*1024];  // 128KB, row stride 2048B, swizzled
  int tid = threadIdx.x;
  int r0 = blockIdx.x * 64;
  char* ab = (char*)At;
  for (int it = 0; it < 64; ++it){
    int idx = it*1024 + tid*4;
    int row = idx >> 10, col = idx & 1023;
    float4 v;
    if (col < 512) v = *reinterpret_cast<const float4*>(h   + (size_t)(r0+row)*512 + col);
    else           v = *reinterpret_cast<const float4*>(agg + (size_t)(r0+row)*512 + (col-512));
    bf16x4 p = {(__bf16)v.x, (__bf16)v.y, (__bf16)v.z, (__bf16)v.w};
    *reinterpret_cast<bf16x4*>(ab + row*2048 + ((col*2) ^ ((row&7)<<4))) = p;
  }
  __syncthreads();
  int lane = tid & 63, wid = tid >> 6;
  int col16 = lane & 15, g = lane >> 4;
  int arow = wid*16 + col16;
  f32x4 acc[16];
  #pragma unroll
  for (int t = 0; t < 16; ++t) acc[t] = f32x4{0.f,0.f,0.f,0.f};
  for (int kk = 0; kk < 32; ++kk){
    bf16x8 af = *reinterpret_cast<const bf16x8*>(ab + arow*2048 + ((kk*64 + g*16) ^ ((arow&7)<<4)));
    #pragma unroll
    for (int t = 0; t < 16; ++t){
      int oc = t*16 + col16;
      bf16x8 bfr = *reinterpret_cast<const bf16x8*>(wn1b + (size_t)oc*1024 + kk*32 + g*8);
      acc[t] = mfma16(af, bfr, acc[t]);
    }
  }
  #pragma unroll
  for (int t = 0; t < 16; ++t){
    int oc = t*16 + col16;
    #pragma unroll
    for (int i2 = 0; i2 < 4; ++i2){
      int row = r0 + wid*16 + g*4 + i2;
      h1[(size_t)row*256 + oc] = (__bf16)silu_f(acc[t][i2] + bn1[oc]);
    }
  }
}

__global__ __launch_bounds__(256) void node2_kernel(const __bf16* __restrict__ h1,
                                                    const __bf16* __restrict__ wn2b,
                                                    const float* __restrict__ bn2,
                                                    float* __restrict__ hout){
  __shared__ __align__(16) __bf16 At[64*256];  // 32KB, row stride 512B, swizzled
  int tid = threadIdx.x;
  int r0 = blockIdx.x * 64;
  char* ab = (char*)At;
  for (int it = 0; it < 8; ++it){
    int idx = it*2048 + tid*8;
    int row = idx >> 8, col = idx & 255;
    bf16x8 v = *reinterpret_cast<const bf16x8*>(h1 + (size_t)(r0+row)*256 + col);
    *reinterpret_cast<bf16x8*>(ab + row*512 + ((col*2) ^ ((row&7)<<4))) = v;
  }
  __syncthreads();
  int lane = tid & 63, wid = tid >> 6;
  int col16 = lane & 15, g = lane >> 4;
  int arow = wid*16 + col16;
  f32x4 acc[16];
  #pragma unroll
  for (int t = 0; t < 16; ++t) acc[t] = f32x4{0.f,0.f,0.f,0.f};
  for (int kk = 0; kk < 8; ++kk){
    bf16x8 af = *reinterpret_cast<const bf16x8*>(ab + arow*512 + ((kk*64 + g*16) ^ ((arow&7)<<4)));
    #pragma unroll
    for (int t = 0; t < 16; ++t){
      int oc = t*16 + col16;
      bf16x8 bfr = *reinterpret_cast<const bf16x8*>(wn2b + (size_t)oc*256 + kk*32 + g*8);
      acc[t] = mfma16(af, bfr, acc[t]);
    }
  }
  #pragma unroll
  for (int t = 0; t < 16; ++t){
    int oc = t*16 + col16;
    #pragma unroll
    for (int i2 = 0; i2 < 4; ++i2){
      int row = r0 + wid*16 + g*4 + i2;
      hout[(size_t)row*256 + oc] = acc[t][i2] + bn2[oc];
    }
  }
}

// -------------------------------------------------------------- launch ----
extern "C" void kernel_launch(void* const* d_in, const int* in_sizes, int n_in,
                              void* d_out, int out_size, void* d_ws, size_t ws_size,
                              hipStream_t stream){
  const float* h   = (const float*)d_in[0];
  const int*   ei  = (const int*)d_in[1];
  const float* ea  = (const float*)d_in[2];
  const float* pos = (const float*)d_in[3];
  const float* We1 = (const float*)d_in[4];
  const float* be1 = (const float*)d_in[5];
  const float* We2 = (const float*)d_in[6];
  const float* be2 = (const float*)d_in[7];
  const float* Wc1 = (const float*)d_in[8];
  const float* bc1 = (const float*)d_in[9];
  const float* Wc2 = (const float*)d_in[10];
  const float* Wn1 = (const float*)d_in[11];
  const float* bn1 = (const float*)d_in[12];
  const float* Wn2 = (const float*)d_in[13];
  const float* bn2 = (const float*)d_in[14];

  char* ws = (char*)d_ws;
  size_t off = 0;
  auto carve = [&](size_t bytes) -> char* {
    char* p = ws + off; off += (bytes + 255) & ~(size_t)255; return p;
  };
  __bf16* wab  = (__bf16*)carve((size_t)1024*512*2);
  __bf16* weaT = (__bf16*)carve((size_t)512*64*2);
  __bf16* we2b = (__bf16*)carve((size_t)512*512*2);
  __bf16* wc1b = (__bf16*)carve((size_t)512*512*2);
  __bf16* wn1b = (__bf16*)carve((size_t)256*1024*2);
  __bf16* wn2b = (__bf16*)carve((size_t)256*256*2);
  __bf16* AB   = (__bf16*)carve((size_t)N_NODES*1024*2);
  float*  agg  = (float*) carve((size_t)N_NODES*512*4);
  __bf16* h1   = (__bf16*)carve((size_t)N_NODES*256*2);

  float* hout = (float*)d_out;
  float* pout = (float*)d_out + (size_t)N_NODES*256;

  hipMemsetAsync(agg, 0, (size_t)N_NODES*512*4, stream);
  hipMemcpyAsync((void*)pout, (const void*)pos, (size_t)N_NODES*3*4,
                 hipMemcpyDeviceToDevice, stream);

  prep_kernel<<<2048, 256, 0, stream>>>(We1, be1, We2, Wc1, Wn1, Wn2,
                                        wab, weaT, we2b, wc1b, wn1b, wn2b);
  gemm_ab_kernel<<<N_NODES/64, 256, 0, stream>>>(h, wab, AB);
  edge_kernel<<<N_EDGES/TE, 512, 0, stream>>>(ei, ea, pos, AB, weaT, we2b, wc1b,
                                              be2, bc1, Wc2, agg, pout);
  node1_kernel<<<N_NODES/64, 256, 0, stream>>>(h, agg, wn1b, bn1, h1);
  node2_kernel<<<N_NODES/64, 256, 0, stream>>>(h1, wn2b, bn2, hout);
}

// Round 4
// 995.516 us; speedup vs baseline: 3.5372x; 1.2136x over previous
//
#include <hip/hip_runtime.h>

#define N_NODES 16384
#define N_EDGES 262144
#define TE 64   // edges per workgroup in edge kernel

typedef __attribute__((ext_vector_type(8))) __bf16 bf16x8;
typedef __attribute__((ext_vector_type(4))) __bf16 bf16x4;
typedef __attribute__((ext_vector_type(4))) float f32x4;
typedef __attribute__((ext_vector_type(16))) float f32x16;

__device__ __forceinline__ float silu_f(float x){ return x / (1.f + __expf(-x)); }

__device__ __forceinline__ f32x4 mfma16(bf16x8 a, bf16x8 b, f32x4 c){
  return __builtin_amdgcn_mfma_f32_16x16x32_bf16(a, b, c, 0, 0, 0);
}
__device__ __forceinline__ f32x16 mfma32(bf16x8 a, bf16x8 b, f32x16 c){
  return __builtin_amdgcn_mfma_f32_32x32x16_bf16(a, b, c, 0, 0, 0);
}

// ---------------------------------------------------------------- prep ----
// weaT [512][64]: k<51 -> We1[o][1024+k]; k==51 -> We1[o][1075] (radial col);
//                 k==52 -> b1[o] (bias via constant-1 input); else 0
__global__ void prep_kernel(const float* __restrict__ We1, const float* __restrict__ be1,
                            const float* __restrict__ We2,
                            const float* __restrict__ Wc1, const float* __restrict__ Wn1,
                            const float* __restrict__ Wn2,
                            __bf16* wab, __bf16* weaT, __bf16* we2b, __bf16* wc1b,
                            __bf16* wn1b, __bf16* wn2b){
  int i = blockIdx.x * 256 + threadIdx.x;
  if (i < 1024*512){
    int o = i >> 9, k = i & 511;
    float v = (o < 512) ? We1[(size_t)o*1076 + k] : We1[(size_t)(o-512)*1076 + 512 + k];
    wab[i] = (__bf16)v;
  }
  if (i < 512*64){
    int o = i >> 6, k = i & 63;
    float v = (k < 51) ? We1[(size_t)o*1076 + 1024 + k]
            : (k == 51 ? We1[(size_t)o*1076 + 1075]
            : (k == 52 ? be1[o] : 0.f));
    weaT[i] = (__bf16)v;
  }
  if (i < 512*512){ we2b[i] = (__bf16)We2[i]; wc1b[i] = (__bf16)Wc1[i]; }
  if (i < 256*1024){ wn1b[i] = (__bf16)Wn1[i]; }
  if (i < 256*256){ wn2b[i] = (__bf16)Wn2[i]; }
}

// ------------------------------------------------- counting sort by row ----
__global__ void hist_kernel(const int* __restrict__ eidx, int* __restrict__ deg){
  int e = blockIdx.x * 256 + threadIdx.x;
  if (e < N_EDGES) atomicAdd(&deg[eidx[e]], 1);
}

__global__ __launch_bounds__(1024) void scan_kernel(const int* __restrict__ deg,
                                                    int* __restrict__ base){
  __shared__ int part[1024];
  int tid = threadIdx.x;
  int b = tid * 16;
  int local[16];
  int s = 0;
  #pragma unroll
  for (int i = 0; i < 16; ++i){ local[i] = deg[b+i]; s += local[i]; }
  part[tid] = s;
  __syncthreads();
  for (int off = 1; off < 1024; off <<= 1){
    int v = 0;
    if (tid >= off) v = part[tid-off];
    __syncthreads();
    part[tid] += v;
    __syncthreads();
  }
  int run = part[tid] - s;   // exclusive prefix of this chunk
  #pragma unroll
  for (int i = 0; i < 16; ++i){ base[b+i] = run; run += local[i]; }
}

__global__ void scatter_kernel(const int* __restrict__ eidx, const int* __restrict__ base,
                               int* __restrict__ cursor, int* __restrict__ perm){
  int e = blockIdx.x * 256 + threadIdx.x;
  if (e < N_EDGES){
    int r = eidx[e];
    int p = atomicAdd(&cursor[r], 1);
    perm[base[r] + p] = e;
  }
}

// ------------------------------------------------------------- gemm AB ----
__global__ __launch_bounds__(256) void gemm_ab_kernel(const float* __restrict__ h,
                                                      const __bf16* __restrict__ wab,
                                                      __bf16* __restrict__ AB){
  __shared__ __align__(16) __bf16 At[64*512];  // 64KB, swizzled
  int tid = threadIdx.x;
  int r0 = blockIdx.x * 64;
  char* ab = (char*)At;
  for (int it = 0; it < 32; ++it){
    int idx = it*1024 + tid*4;
    int row = idx >> 9, col = idx & 511;
    float4 v = *reinterpret_cast<const float4*>(h + (size_t)(r0+row)*512 + col);
    bf16x4 p = {(__bf16)v.x, (__bf16)v.y, (__bf16)v.z, (__bf16)v.w};
    *reinterpret_cast<bf16x4*>(ab + row*1024 + ((col*2) ^ ((row&7)<<4))) = p;
  }
  __syncthreads();
  int lane = tid & 63, wid = tid >> 6;
  int col16 = lane & 15, g = lane >> 4;
  int arow = wid*16 + col16;
  for (int cc = 0; cc < 8; ++cc){
    f32x4 acc[8];
    #pragma unroll
    for (int t = 0; t < 8; ++t) acc[t] = f32x4{0.f,0.f,0.f,0.f};
    for (int kk = 0; kk < 16; ++kk){
      bf16x8 af = *reinterpret_cast<const bf16x8*>(ab + arow*1024 + ((kk*64 + g*16) ^ ((arow&7)<<4)));
      #pragma unroll
      for (int t = 0; t < 8; ++t){
        int oc = cc*128 + t*16 + col16;
        bf16x8 bfr = *reinterpret_cast<const bf16x8*>(wab + (size_t)oc*512 + kk*32 + g*8);
        acc[t] = mfma16(af, bfr, acc[t]);
      }
    }
    #pragma unroll
    for (int t = 0; t < 8; ++t){
      int oc = cc*128 + t*16 + col16;
      #pragma unroll
      for (int i2 = 0; i2 < 4; ++i2){
        int row = r0 + wid*16 + g*4 + i2;
        AB[(size_t)row*1024 + oc] = (__bf16)acc[t][i2];
      }
    }
  }
}

// ------------------------------------------------------- fused edge op ----
// Edges processed in row-sorted order (perm). 512 threads = 8 waves; wave
// owns a 64-col strip. Segmented reductions replace per-element atomics.
__global__ __launch_bounds__(512, 4) void edge_kernel(
    const int* __restrict__ eidx, const int* __restrict__ perm,
    const float* __restrict__ edge_attr,
    const float* __restrict__ pos,
    const __bf16* __restrict__ AB, const __bf16* __restrict__ weaT,
    const __bf16* __restrict__ we2b, const __bf16* __restrict__ wc1b,
    const float* __restrict__ b2,
    const float* __restrict__ bc1, const float* __restrict__ wc2,
    float* __restrict__ agg, float* __restrict__ pos_out)
{
  __shared__ __align__(16) __bf16 e1t[TE*512];   // 64KB swizzled (e1, later e2)
  __shared__ __align__(16) __bf16 eat[TE*64];    // 8KB  swizzled (ea|radial|1|pad)
  __shared__ float diffs[3][TE];
  __shared__ float rad[TE];
  __shared__ int   rl[TE], cl[TE], el[TE];
  __shared__ float cupart[8][TE];
  __shared__ float cuf[TE];

  int tid = threadIdx.x;
  int e0 = blockIdx.x * TE;

  if (tid < TE){
    int eid = perm[e0 + tid];
    el[tid] = eid;
    int r = eidx[eid], c = eidx[N_EDGES + eid];
    rl[tid] = r; cl[tid] = c;
    float dx = pos[r*3+0]-pos[c*3+0];
    float dy = pos[r*3+1]-pos[c*3+1];
    float dz = pos[r*3+2]-pos[c*3+2];
    diffs[0][tid]=dx; diffs[1][tid]=dy; diffs[2][tid]=dz;
    float rr = dx*dx + dy*dy + dz*dz;
    rad[tid] = fminf(fmaxf(rr, 1e-8f), 100.f);
  }
  __syncthreads();

  // stage edge_attr (+radial k=51, one k=52, zero pad) swizzled bf16 [TE][64]
  {
    char* eb = (char*)eat;
    for (int i = tid; i < TE*64; i += 512){
      int e = i >> 6, k = i & 63;
      float v = (k < 51) ? edge_attr[(size_t)el[e]*51 + k]
              : (k == 51 ? rad[e] : (k == 52 ? 1.0f : 0.f));
      *reinterpret_cast<__bf16*>(eb + e*128 + ((k*2) ^ ((e&7)<<4))) = (__bf16)v;
    }
  }
  // prefill e1t with gather-sum (bf16, swizzled); bias comes via weaT k=52
  {
    int e = tid >> 3, q = tid & 7;
    size_t baseR = (size_t)rl[e]*1024;
    size_t baseC = (size_t)cl[e]*1024 + 512;
    char* eb = (char*)e1t;
    #pragma unroll
    for (int c = 0; c < 8; ++c){
      int o0 = q*8 + c*64;
      bf16x8 ga = *reinterpret_cast<const bf16x8*>(AB + baseR + o0);
      bf16x8 gb = *reinterpret_cast<const bf16x8*>(AB + baseC + o0);
      bf16x8 outv;
      #pragma unroll
      for (int j = 0; j < 8; ++j) outv[j] = (__bf16)((float)ga[j] + (float)gb[j]);
      *reinterpret_cast<bf16x8*>(eb + e*1024 + ((o0*2) ^ ((e&7)<<4))) = outv;
    }
  }
  __syncthreads();

  int lane = tid & 63, wid = tid >> 6;
  int c31 = lane & 31, hi = lane >> 5;
  int colbase = wid * 64;
  char* e1b = (char*)e1t;

  // P0: e1 = silu(prefill + ea@Wea^T)  (K=64, bias folded at k=52)
  {
    f32x16 acc[2][2];
    #pragma unroll
    for (int rt = 0; rt < 2; ++rt)
      #pragma unroll
      for (int ct = 0; ct < 2; ++ct)
        #pragma unroll
        for (int r = 0; r < 16; ++r) acc[rt][ct][r] = 0.f;
    const char* eb = (const char*)eat;
    #pragma unroll
    for (int kk = 0; kk < 4; ++kk){
      bf16x8 af[2];
      #pragma unroll
      for (int rt = 0; rt < 2; ++rt){
        int arow = rt*32 + c31;
        af[rt] = *reinterpret_cast<const bf16x8*>(eb + arow*128 + ((kk*32 + hi*16) ^ ((arow&7)<<4)));
      }
      #pragma unroll
      for (int ct = 0; ct < 2; ++ct){
        int oc = colbase + ct*32 + c31;
        bf16x8 bfr = *reinterpret_cast<const bf16x8*>(weaT + (size_t)oc*64 + kk*16 + hi*8);
        #pragma unroll
        for (int rt = 0; rt < 2; ++rt) acc[rt][ct] = mfma32(af[rt], bfr, acc[rt][ct]);
      }
    }
    #pragma unroll
    for (int rt = 0; rt < 2; ++rt){
      #pragma unroll
      for (int reg = 0; reg < 16; ++reg){
        int row = rt*32 + (reg&3) + 8*(reg>>2) + 4*hi;
        #pragma unroll
        for (int ct = 0; ct < 2; ++ct){
          int oc = colbase + ct*32 + c31;
          __bf16* p = reinterpret_cast<__bf16*>(e1b + row*1024 + ((oc*2) ^ ((row&7)<<4)));
          float v = (float)*p + acc[rt][ct][reg];
          *p = (__bf16)silu_f(v);
        }
      }
    }
  }
  __syncthreads();

  // P1: e2 = silu(e1 @ We2^T + b2); e2 -> e1t (no atomics here)
  {
    f32x16 acc[2][2];
    #pragma unroll
    for (int rt = 0; rt < 2; ++rt)
      #pragma unroll
      for (int ct = 0; ct < 2; ++ct)
        #pragma unroll
        for (int r = 0; r < 16; ++r) acc[rt][ct][r] = 0.f;
    const __bf16* Brow = we2b + (size_t)(colbase + c31)*512 + hi*8;
    bf16x8 bcur[2], bnxt[2];
    #pragma unroll
    for (int ct = 0; ct < 2; ++ct) bcur[ct] = *reinterpret_cast<const bf16x8*>(Brow + ct*16384);
    for (int kk = 0; kk < 32; ++kk){
      if (kk < 31){
        #pragma unroll
        for (int ct = 0; ct < 2; ++ct)
          bnxt[ct] = *reinterpret_cast<const bf16x8*>(Brow + (kk+1)*16 + ct*16384);
      }
      bf16x8 af[2];
      #pragma unroll
      for (int rt = 0; rt < 2; ++rt){
        int arow = rt*32 + c31;
        af[rt] = *reinterpret_cast<const bf16x8*>(e1b + arow*1024 + ((kk*32 + hi*16) ^ ((arow&7)<<4)));
      }
      #pragma unroll
      for (int ct = 0; ct < 2; ++ct)
        #pragma unroll
        for (int rt = 0; rt < 2; ++rt)
          acc[rt][ct] = mfma32(af[rt], bcur[ct], acc[rt][ct]);
      #pragma unroll
      for (int ct = 0; ct < 2; ++ct) bcur[ct] = bnxt[ct];
    }
    __syncthreads();   // all waves done READING e1t
    float b2v[2];
    #pragma unroll
    for (int ct = 0; ct < 2; ++ct) b2v[ct] = b2[colbase + ct*32 + c31];
    #pragma unroll
    for (int rt = 0; rt < 2; ++rt){
      #pragma unroll
      for (int reg = 0; reg < 16; ++reg){
        int row = rt*32 + (reg&3) + 8*(reg>>2) + 4*hi;
        #pragma unroll
        for (int ct = 0; ct < 2; ++ct){
          int oc = colbase + ct*32 + c31;
          float v = silu_f(acc[rt][ct][reg] + b2v[ct]);
          *reinterpret_cast<__bf16*>(e1b + row*1024 + ((oc*2) ^ ((row&7)<<4))) = (__bf16)v;
        }
      }
    }
  }
  __syncthreads();

  // AGG: segmented per-column sum over row-sorted edges; 1 atomic per
  // distinct row per column (rows repeat ~16x under the sort)
  {
    int col = tid;  // 512 threads == 512 cols
    const char* e2b = (const char*)e1t;
    float a = 0.f;
    int prev = rl[0];
    for (int e = 0; e < TE; ++e){
      int r = rl[e];   // broadcast LDS read, wave-uniform branch
      if (r != prev){
        atomicAdd(&agg[(size_t)prev*512 + col], a);
        a = 0.f; prev = r;
      }
      a += (float)*reinterpret_cast<const __bf16*>(e2b + e*1024 + ((col*2) ^ ((e&7)<<4)));
    }
    atomicAdd(&agg[(size_t)prev*512 + col], a);
  }

  // P2: c1 = silu(e2 @ Wc1^T + bc1); cu partial = c1 . wc2
  {
    f32x16 acc[2][2];
    #pragma unroll
    for (int rt = 0; rt < 2; ++rt)
      #pragma unroll
      for (int ct = 0; ct < 2; ++ct)
        #pragma unroll
        for (int r = 0; r < 16; ++r) acc[rt][ct][r] = 0.f;
    const __bf16* Brow = wc1b + (size_t)(colbase + c31)*512 + hi*8;
    bf16x8 bcur[2], bnxt[2];
    #pragma unroll
    for (int ct = 0; ct < 2; ++ct) bcur[ct] = *reinterpret_cast<const bf16x8*>(Brow + ct*16384);
    for (int kk = 0; kk < 32; ++kk){
      if (kk < 31){
        #pragma unroll
        for (int ct = 0; ct < 2; ++ct)
          bnxt[ct] = *reinterpret_cast<const bf16x8*>(Brow + (kk+1)*16 + ct*16384);
      }
      bf16x8 af[2];
      #pragma unroll
      for (int rt = 0; rt < 2; ++rt){
        int arow = rt*32 + c31;
        af[rt] = *reinterpret_cast<const bf16x8*>(e1b + arow*1024 + ((kk*32 + hi*16) ^ ((arow&7)<<4)));
      }
      #pragma unroll
      for (int ct = 0; ct < 2; ++ct)
        #pragma unroll
        for (int rt = 0; rt < 2; ++rt)
          acc[rt][ct] = mfma32(af[rt], bcur[ct], acc[rt][ct]);
      #pragma unroll
      for (int ct = 0; ct < 2; ++ct) bcur[ct] = bnxt[ct];
    }
    float bcv[2], wcv[2];
    #pragma unroll
    for (int ct = 0; ct < 2; ++ct){
      int oc = colbase + ct*32 + c31;
      bcv[ct] = bc1[oc]; wcv[ct] = wc2[oc];
    }
    #pragma unroll
    for (int rt = 0; rt < 2; ++rt){
      #pragma unroll
      for (int reg = 0; reg < 16; ++reg){
        float pv = 0.f;
        #pragma unroll
        for (int ct = 0; ct < 2; ++ct)
          pv += silu_f(acc[rt][ct][reg] + bcv[ct]) * wcv[ct];
        #pragma unroll
        for (int off = 1; off < 32; off <<= 1) pv += __shfl_xor(pv, off, 64);
        if (c31 == 0){
          int row = rt*32 + (reg&3) + 8*(reg>>2) + 4*hi;
          cupart[wid][row] = pv;
        }
      }
    }
  }
  __syncthreads();

  if (tid < TE){
    float cu0 = 0.f;
    #pragma unroll
    for (int w = 0; w < 8; ++w) cu0 += cupart[w][tid];
    float cu = fminf(fmaxf(cu0, -1.f), 1.f);
    if (!isfinite(cu0)) cu = 0.f;
    cuf[tid] = cu;
  }
  __syncthreads();

  // POS: segmented per-axis sum (3 threads), 1 atomic per distinct row
  if (tid < 3){
    int d = tid;
    float a = 0.f;
    int prev = rl[0];
    for (int e = 0; e < TE; ++e){
      int r = rl[e];
      if (r != prev){
        atomicAdd(&pos_out[(size_t)prev*3 + d], a);
        a = 0.f; prev = r;
      }
      a += diffs[d][e] * cuf[e];
    }
    atomicAdd(&pos_out[(size_t)prev*3 + d], a);
  }
}

// ------------------------------------------------------------ node MLP ----
__global__ __launch_bounds__(256) void node1_kernel(const float* __restrict__ h,
                                                    const float* __restrict__ agg,
                                                    const __bf16* __restrict__ wn1b,
                                                    const float* __restrict__ bn1,
                                                    __bf16* __restrict__ h1){
  __shared__ __align__(16) __bf16 At[64*1024];  // 128KB, row stride 2048B, swizzled
  int tid = threadIdx.x;
  int r0 = blockIdx.x * 64;
  char* ab = (char*)At;
  for (int it = 0; it < 64; ++it){
    int idx = it*1024 + tid*4;
    int row = idx >> 10, col = idx & 1023;
    float4 v;
    if (col < 512) v = *reinterpret_cast<const float4*>(h   + (size_t)(r0+row)*512 + col);
    else           v = *reinterpret_cast<const float4*>(agg + (size_t)(r0+row)*512 + (col-512));
    bf16x4 p = {(__bf16)v.x, (__bf16)v.y, (__bf16)v.z, (__bf16)v.w};
    *reinterpret_cast<bf16x4*>(ab + row*2048 + ((col*2) ^ ((row&7)<<4))) = p;
  }
  __syncthreads();
  int lane = tid & 63, wid = tid >> 6;
  int col16 = lane & 15, g = lane >> 4;
  int arow = wid*16 + col16;
  f32x4 acc[16];
  #pragma unroll
  for (int t = 0; t < 16; ++t) acc[t] = f32x4{0.f,0.f,0.f,0.f};
  for (int kk = 0; kk < 32; ++kk){
    bf16x8 af = *reinterpret_cast<const bf16x8*>(ab + arow*2048 + ((kk*64 + g*16) ^ ((arow&7)<<4)));
    #pragma unroll
    for (int t = 0; t < 16; ++t){
      int oc = t*16 + col16;
      bf16x8 bfr = *reinterpret_cast<const bf16x8*>(wn1b + (size_t)oc*1024 + kk*32 + g*8);
      acc[t] = mfma16(af, bfr, acc[t]);
    }
  }
  #pragma unroll
  for (int t = 0; t < 16; ++t){
    int oc = t*16 + col16;
    #pragma unroll
    for (int i2 = 0; i2 < 4; ++i2){
      int row = r0 + wid*16 + g*4 + i2;
      h1[(size_t)row*256 + oc] = (__bf16)silu_f(acc[t][i2] + bn1[oc]);
    }
  }
}

__global__ __launch_bounds__(256) void node2_kernel(const __bf16* __restrict__ h1,
                                                    const __bf16* __restrict__ wn2b,
                                                    const float* __restrict__ bn2,
                                                    float* __restrict__ hout){
  __shared__ __align__(16) __bf16 At[64*256];  // 32KB, row stride 512B, swizzled
  int tid = threadIdx.x;
  int r0 = blockIdx.x * 64;
  char* ab = (char*)At;
  for (int it = 0; it < 8; ++it){
    int idx = it*2048 + tid*8;
    int row = idx >> 8, col = idx & 255;
    bf16x8 v = *reinterpret_cast<const bf16x8*>(h1 + (size_t)(r0+row)*256 + col);
    *reinterpret_cast<bf16x8*>(ab + row*512 + ((col*2) ^ ((row&7)<<4))) = v;
  }
  __syncthreads();
  int lane = tid & 63, wid = tid >> 6;
  int col16 = lane & 15, g = lane >> 4;
  int arow = wid*16 + col16;
  f32x4 acc[16];
  #pragma unroll
  for (int t = 0; t < 16; ++t) acc[t] = f32x4{0.f,0.f,0.f,0.f};
  for (int kk = 0; kk < 8; ++kk){
    bf16x8 af = *reinterpret_cast<const bf16x8*>(ab + arow*512 + ((kk*64 + g*16) ^ ((arow&7)<<4)));
    #pragma unroll
    for (int t = 0; t < 16; ++t){
      int oc = t*16 + col16;
      bf16x8 bfr = *reinterpret_cast<const bf16x8*>(wn2b + (size_t)oc*256 + kk*32 + g*8);
      acc[t] = mfma16(af, bfr, acc[t]);
    }
  }
  #pragma unroll
  for (int t = 0; t < 16; ++t){
    int oc = t*16 + col16;
    #pragma unroll
    for (int i2 = 0; i2 < 4; ++i2){
      int row = r0 + wid*16 + g*4 + i2;
      hout[(size_t)row*256 + oc] = acc[t][i2] + bn2[oc];
    }
  }
}

// -------------------------------------------------------------- launch ----
extern "C" void kernel_launch(void* const* d_in, const int* in_sizes, int n_in,
                              void* d_out, int out_size, void* d_ws, size_t ws_size,
                              hipStream_t stream){
  const float* h   = (const float*)d_in[0];
  const int*   ei  = (const int*)d_in[1];
  const float* ea  = (const float*)d_in[2];
  const float* pos = (const float*)d_in[3];
  const float* We1 = (const float*)d_in[4];
  const float* be1 = (const float*)d_in[5];
  const float* We2 = (const float*)d_in[6];
  const float* be2 = (const float*)d_in[7];
  const float* Wc1 = (const float*)d_in[8];
  const float* bc1 = (const float*)d_in[9];
  const float* Wc2 = (const float*)d_in[10];
  const float* Wn1 = (const float*)d_in[11];
  const float* bn1 = (const float*)d_in[12];
  const float* Wn2 = (const float*)d_in[13];
  const float* bn2 = (const float*)d_in[14];

  char* ws = (char*)d_ws;
  size_t off = 0;
  auto carve = [&](size_t bytes) -> char* {
    char* p = ws + off; off += (bytes + 255) & ~(size_t)255; return p;
  };
  __bf16* wab  = (__bf16*)carve((size_t)1024*512*2);
  __bf16* weaT = (__bf16*)carve((size_t)512*64*2);
  __bf16* we2b = (__bf16*)carve((size_t)512*512*2);
  __bf16* wc1b = (__bf16*)carve((size_t)512*512*2);
  __bf16* wn1b = (__bf16*)carve((size_t)256*1024*2);
  __bf16* wn2b = (__bf16*)carve((size_t)256*256*2);
  __bf16* AB   = (__bf16*)carve((size_t)N_NODES*1024*2);
  float*  agg  = (float*) carve((size_t)N_NODES*512*4);
  __bf16* h1   = (__bf16*)carve((size_t)N_NODES*256*2);
  int*    deg    = (int*) carve((size_t)N_NODES*4);
  int*    basep  = (int*) carve((size_t)N_NODES*4);
  int*    cursor = (int*) carve((size_t)N_NODES*4);
  int*    perm   = (int*) carve((size_t)N_EDGES*4);

  float* hout = (float*)d_out;
  float* pout = (float*)d_out + (size_t)N_NODES*256;

  hipMemsetAsync(agg, 0, (size_t)N_NODES*512*4, stream);
  hipMemsetAsync(deg, 0, (size_t)N_NODES*4, stream);
  hipMemsetAsync(cursor, 0, (size_t)N_NODES*4, stream);
  hipMemcpyAsync((void*)pout, (const void*)pos, (size_t)N_NODES*3*4,
                 hipMemcpyDeviceToDevice, stream);

  prep_kernel<<<2048, 256, 0, stream>>>(We1, be1, We2, Wc1, Wn1, Wn2,
                                        wab, weaT, we2b, wc1b, wn1b, wn2b);
  hist_kernel<<<N_EDGES/256, 256, 0, stream>>>(ei, deg);
  scan_kernel<<<1, 1024, 0, stream>>>(deg, basep);
  scatter_kernel<<<N_EDGES/256, 256, 0, stream>>>(ei, basep, cursor, perm);
  gemm_ab_kernel<<<N_NODES/64, 256, 0, stream>>>(h, wab, AB);
  edge_kernel<<<N_EDGES/TE, 512, 0, stream>>>(ei, perm, ea, pos, AB, weaT, we2b, wc1b,
                                              be2, bc1, Wc2, agg, pout);
  node1_kernel<<<N_NODES/64, 256, 0, stream>>>(h, agg, wn1b, bn1, h1);
  node2_kernel<<<N_NODES/64, 256, 0, stream>>>(h1, wn2b, bn2, hout);
}

// Round 5
// 965.510 us; speedup vs baseline: 3.6471x; 1.0311x over previous
//
#include <hip/hip_runtime.h>

#define N_NODES 16384
#define N_EDGES 262144
#define TE 64   // edges per workgroup in edge kernel

typedef __attribute__((ext_vector_type(8))) __bf16 bf16x8;
typedef __attribute__((ext_vector_type(4))) __bf16 bf16x4;
typedef __attribute__((ext_vector_type(4))) float f32x4;
typedef __attribute__((ext_vector_type(16))) float f32x16;

__device__ __forceinline__ float silu_f(float x){ return x / (1.f + __expf(-x)); }

__device__ __forceinline__ f32x4 mfma16(bf16x8 a, bf16x8 b, f32x4 c){
  return __builtin_amdgcn_mfma_f32_16x16x32_bf16(a, b, c, 0, 0, 0);
}
__device__ __forceinline__ f32x16 mfma32(bf16x8 a, bf16x8 b, f32x16 c){
  return __builtin_amdgcn_mfma_f32_32x32x16_bf16(a, b, c, 0, 0, 0);
}

// ---------------------------------------------------------------- prep ----
// weaT [512][64]: k<51 -> We1[o][1024+k]; k==51 -> We1[o][1075] (radial col);
//                 k==52 -> b1[o] (bias via constant-1 input); else 0
__global__ void prep_kernel(const float* __restrict__ We1, const float* __restrict__ be1,
                            const float* __restrict__ We2,
                            const float* __restrict__ Wc1, const float* __restrict__ Wn1,
                            const float* __restrict__ Wn2,
                            __bf16* wab, __bf16* weaT, __bf16* we2b, __bf16* wc1b,
                            __bf16* wn1b, __bf16* wn2b){
  int i = blockIdx.x * 256 + threadIdx.x;
  if (i < 1024*512){
    int o = i >> 9, k = i & 511;
    float v = (o < 512) ? We1[(size_t)o*1076 + k] : We1[(size_t)(o-512)*1076 + 512 + k];
    wab[i] = (__bf16)v;
  }
  if (i < 512*64){
    int o = i >> 6, k = i & 63;
    float v = (k < 51) ? We1[(size_t)o*1076 + 1024 + k]
            : (k == 51 ? We1[(size_t)o*1076 + 1075]
            : (k == 52 ? be1[o] : 0.f));
    weaT[i] = (__bf16)v;
  }
  if (i < 512*512){ we2b[i] = (__bf16)We2[i]; wc1b[i] = (__bf16)Wc1[i]; }
  if (i < 256*1024){ wn1b[i] = (__bf16)Wn1[i]; }
  if (i < 256*256){ wn2b[i] = (__bf16)Wn2[i]; }
}

// ------------------------------------------------- counting sort by row ----
__global__ void hist_kernel(const int* __restrict__ eidx, int* __restrict__ deg){
  int e = blockIdx.x * 256 + threadIdx.x;
  if (e < N_EDGES) atomicAdd(&deg[eidx[e]], 1);
}

__global__ __launch_bounds__(1024) void scan_kernel(const int* __restrict__ deg,
                                                    int* __restrict__ base){
  __shared__ int part[1024];
  int tid = threadIdx.x;
  int b = tid * 16;
  int local[16];
  int s = 0;
  #pragma unroll
  for (int i = 0; i < 16; ++i){ local[i] = deg[b+i]; s += local[i]; }
  part[tid] = s;
  __syncthreads();
  for (int off = 1; off < 1024; off <<= 1){
    int v = 0;
    if (tid >= off) v = part[tid-off];
    __syncthreads();
    part[tid] += v;
    __syncthreads();
  }
  int run = part[tid] - s;   // exclusive prefix of this chunk
  #pragma unroll
  for (int i = 0; i < 16; ++i){ base[b+i] = run; run += local[i]; }
}

__global__ void scatter_kernel(const int* __restrict__ eidx, const int* __restrict__ base,
                               int* __restrict__ cursor, int* __restrict__ perm){
  int e = blockIdx.x * 256 + threadIdx.x;
  if (e < N_EDGES){
    int r = eidx[e];
    int p = atomicAdd(&cursor[r], 1);
    perm[base[r] + p] = e;
  }
}

// ------------------------------------------------------------- gemm AB ----
__global__ __launch_bounds__(256) void gemm_ab_kernel(const float* __restrict__ h,
                                                      const __bf16* __restrict__ wab,
                                                      __bf16* __restrict__ AB){
  __shared__ __align__(16) __bf16 At[64*512];  // 64KB, swizzled
  int tid = threadIdx.x;
  int r0 = blockIdx.x * 64;
  char* ab = (char*)At;
  for (int it = 0; it < 32; ++it){
    int idx = it*1024 + tid*4;
    int row = idx >> 9, col = idx & 511;
    float4 v = *reinterpret_cast<const float4*>(h + (size_t)(r0+row)*512 + col);
    bf16x4 p = {(__bf16)v.x, (__bf16)v.y, (__bf16)v.z, (__bf16)v.w};
    *reinterpret_cast<bf16x4*>(ab + row*1024 + ((col*2) ^ ((row&7)<<4))) = p;
  }
  __syncthreads();
  int lane = tid & 63, wid = tid >> 6;
  int col16 = lane & 15, g = lane >> 4;
  int arow = wid*16 + col16;
  for (int cc = 0; cc < 8; ++cc){
    f32x4 acc[8];
    #pragma unroll
    for (int t = 0; t < 8; ++t) acc[t] = f32x4{0.f,0.f,0.f,0.f};
    for (int kk = 0; kk < 16; ++kk){
      bf16x8 af = *reinterpret_cast<const bf16x8*>(ab + arow*1024 + ((kk*64 + g*16) ^ ((arow&7)<<4)));
      #pragma unroll
      for (int t = 0; t < 8; ++t){
        int oc = cc*128 + t*16 + col16;
        bf16x8 bfr = *reinterpret_cast<const bf16x8*>(wab + (size_t)oc*512 + kk*32 + g*8);
        acc[t] = mfma16(af, bfr, acc[t]);
      }
    }
    #pragma unroll
    for (int t = 0; t < 8; ++t){
      int oc = cc*128 + t*16 + col16;
      #pragma unroll
      for (int i2 = 0; i2 < 4; ++i2){
        int row = r0 + wid*16 + g*4 + i2;
        AB[(size_t)row*1024 + oc] = (__bf16)acc[t][i2];
      }
    }
  }
}

// ----------------------------------------------- K=512 phase w/ ring PF ----
// 4-deep register ring prefetch of B fragments (statically indexed), covers
// ~200cy L2 latency with ~4x32cy of MFMA work.
__device__ __forceinline__ void gemm_phase(const char* e1b, const __bf16* __restrict__ Brow,
                                           int c31, int hi, f32x16 acc[2][2]){
  bf16x8 bq[4][2];
  #pragma unroll
  for (int s = 0; s < 4; ++s)
    #pragma unroll
    for (int ct = 0; ct < 2; ++ct)
      bq[s][ct] = *reinterpret_cast<const bf16x8*>(Brow + s*16 + ct*16384);
  for (int kkb = 0; kkb < 8; ++kkb){
    #pragma unroll
    for (int s = 0; s < 4; ++s){
      int kk = kkb*4 + s;
      bf16x8 af[2];
      #pragma unroll
      for (int rt = 0; rt < 2; ++rt){
        int arow = rt*32 + c31;
        af[rt] = *reinterpret_cast<const bf16x8*>(e1b + arow*1024 + ((kk*32 + hi*16) ^ ((arow&7)<<4)));
      }
      #pragma unroll
      for (int ct = 0; ct < 2; ++ct)
        #pragma unroll
        for (int rt = 0; rt < 2; ++rt)
          acc[rt][ct] = mfma32(af[rt], bq[s][ct], acc[rt][ct]);
      if (kkb < 7){
        #pragma unroll
        for (int ct = 0; ct < 2; ++ct)
          bq[s][ct] = *reinterpret_cast<const bf16x8*>(Brow + (kk+4)*16 + ct*16384);
      }
    }
  }
}

// ------------------------------------------------------- fused edge op ----
// Edges processed in row-sorted order (perm). 512 threads = 8 waves; wave
// owns a 64-col strip. Segmented reductions (ballot boundary mask, fully
// unrolled) replace per-element atomics.
__global__ __launch_bounds__(512, 4) void edge_kernel(
    const int* __restrict__ eidx, const int* __restrict__ perm,
    const float* __restrict__ edge_attr,
    const float* __restrict__ pos,
    const __bf16* __restrict__ AB, const __bf16* __restrict__ weaT,
    const __bf16* __restrict__ we2b, const __bf16* __restrict__ wc1b,
    const float* __restrict__ b2,
    const float* __restrict__ bc1, const float* __restrict__ wc2,
    float* __restrict__ agg, float* __restrict__ pos_out)
{
  __shared__ __align__(16) __bf16 e1t[TE*512];   // 64KB swizzled (e1, later e2)
  __shared__ __align__(16) __bf16 eat[TE*64];    // 8KB  swizzled (ea|radial|1|pad)
  __shared__ float diffs[3][TE];
  __shared__ float rad[TE];
  __shared__ int   rl[TE], cl[TE], el[TE];
  __shared__ float cupart[8][TE];
  __shared__ float cuf[TE];
  __shared__ unsigned long long segmask;

  int tid = threadIdx.x;
  int e0 = blockIdx.x * TE;

  if (tid < TE){
    int eid = perm[e0 + tid];
    el[tid] = eid;
    int r = eidx[eid], c = eidx[N_EDGES + eid];
    rl[tid] = r; cl[tid] = c;
    float dx = pos[r*3+0]-pos[c*3+0];
    float dy = pos[r*3+1]-pos[c*3+1];
    float dz = pos[r*3+2]-pos[c*3+2];
    diffs[0][tid]=dx; diffs[1][tid]=dy; diffs[2][tid]=dz;
    float rr = dx*dx + dy*dy + dz*dz;
    rad[tid] = fminf(fmaxf(rr, 1e-8f), 100.f);
  }
  __syncthreads();

  // segment-boundary mask over the sorted 64 rows (wave 0 only)
  if (tid < 64){
    unsigned long long m = __ballot(tid > 0 && rl[tid] != rl[tid-1]);
    if (tid == 0) segmask = m;
  }

  // stage edge_attr (+radial k=51, one k=52, zero pad) swizzled bf16 [TE][64]
  {
    char* eb = (char*)eat;
    for (int i = tid; i < TE*64; i += 512){
      int e = i >> 6, k = i & 63;
      float v = (k < 51) ? edge_attr[(size_t)el[e]*51 + k]
              : (k == 51 ? rad[e] : (k == 52 ? 1.0f : 0.f));
      *reinterpret_cast<__bf16*>(eb + e*128 + ((k*2) ^ ((e&7)<<4))) = (__bf16)v;
    }
  }
  // prefill e1t with gather-sum (bf16, swizzled); bias comes via weaT k=52
  {
    int e = tid >> 3, q = tid & 7;
    size_t baseR = (size_t)rl[e]*1024;
    size_t baseC = (size_t)cl[e]*1024 + 512;
    char* eb = (char*)e1t;
    #pragma unroll
    for (int c = 0; c < 8; ++c){
      int o0 = q*8 + c*64;
      bf16x8 ga = *reinterpret_cast<const bf16x8*>(AB + baseR + o0);
      bf16x8 gb = *reinterpret_cast<const bf16x8*>(AB + baseC + o0);
      bf16x8 outv;
      #pragma unroll
      for (int j = 0; j < 8; ++j) outv[j] = (__bf16)((float)ga[j] + (float)gb[j]);
      *reinterpret_cast<bf16x8*>(eb + e*1024 + ((o0*2) ^ ((e&7)<<4))) = outv;
    }
  }
  __syncthreads();

  int lane = tid & 63, wid = tid >> 6;
  int c31 = lane & 31, hi = lane >> 5;
  int colbase = wid * 64;
  char* e1b = (char*)e1t;

  // P0: e1 = silu(prefill + ea@Wea^T)  (K=64, bias folded at k=52)
  {
    f32x16 acc[2][2];
    #pragma unroll
    for (int rt = 0; rt < 2; ++rt)
      #pragma unroll
      for (int ct = 0; ct < 2; ++ct)
        #pragma unroll
        for (int r = 0; r < 16; ++r) acc[rt][ct][r] = 0.f;
    const char* eb = (const char*)eat;
    #pragma unroll
    for (int kk = 0; kk < 4; ++kk){
      bf16x8 af[2];
      #pragma unroll
      for (int rt = 0; rt < 2; ++rt){
        int arow = rt*32 + c31;
        af[rt] = *reinterpret_cast<const bf16x8*>(eb + arow*128 + ((kk*32 + hi*16) ^ ((arow&7)<<4)));
      }
      #pragma unroll
      for (int ct = 0; ct < 2; ++ct){
        int oc = colbase + ct*32 + c31;
        bf16x8 bfr = *reinterpret_cast<const bf16x8*>(weaT + (size_t)oc*64 + kk*16 + hi*8);
        #pragma unroll
        for (int rt = 0; rt < 2; ++rt) acc[rt][ct] = mfma32(af[rt], bfr, acc[rt][ct]);
      }
    }
    #pragma unroll
    for (int rt = 0; rt < 2; ++rt){
      #pragma unroll
      for (int reg = 0; reg < 16; ++reg){
        int row = rt*32 + (reg&3) + 8*(reg>>2) + 4*hi;
        #pragma unroll
        for (int ct = 0; ct < 2; ++ct){
          int oc = colbase + ct*32 + c31;
          __bf16* p = reinterpret_cast<__bf16*>(e1b + row*1024 + ((oc*2) ^ ((row&7)<<4)));
          float v = (float)*p + acc[rt][ct][reg];
          *p = (__bf16)silu_f(v);
        }
      }
    }
  }
  __syncthreads();

  // P1: e2 = silu(e1 @ We2^T + b2); e2 -> e1t (no atomics here)
  {
    f32x16 acc[2][2];
    #pragma unroll
    for (int rt = 0; rt < 2; ++rt)
      #pragma unroll
      for (int ct = 0; ct < 2; ++ct)
        #pragma unroll
        for (int r = 0; r < 16; ++r) acc[rt][ct][r] = 0.f;
    gemm_phase(e1b, we2b + (size_t)(colbase + c31)*512 + hi*8, c31, hi, acc);
    __syncthreads();   // all waves done READING e1t
    float b2v[2];
    #pragma unroll
    for (int ct = 0; ct < 2; ++ct) b2v[ct] = b2[colbase + ct*32 + c31];
    #pragma unroll
    for (int rt = 0; rt < 2; ++rt){
      #pragma unroll
      for (int reg = 0; reg < 16; ++reg){
        int row = rt*32 + (reg&3) + 8*(reg>>2) + 4*hi;
        #pragma unroll
        for (int ct = 0; ct < 2; ++ct){
          int oc = colbase + ct*32 + c31;
          float v = silu_f(acc[rt][ct][reg] + b2v[ct]);
          *reinterpret_cast<__bf16*>(e1b + row*1024 + ((oc*2) ^ ((row&7)<<4))) = (__bf16)v;
        }
      }
    }
  }
  __syncthreads();

  // AGG: segmented per-column sum over row-sorted edges; boundary mask is a
  // register -> all 64 ds_reads pipeline (no load-dependent branch)
  {
    int col = tid;  // 512 threads == 512 cols
    const char* e2b = (const char*)e1t;
    unsigned long long m = segmask;
    float a = 0.f;
    #pragma unroll
    for (int e = 0; e < TE; ++e){
      if (e > 0 && ((m >> e) & 1)){
        atomicAdd(&agg[(size_t)rl[e-1]*512 + col], a);
        a = 0.f;
      }
      a += (float)*reinterpret_cast<const __bf16*>(e2b + e*1024 + ((col*2) ^ ((e&7)<<4)));
    }
    atomicAdd(&agg[(size_t)rl[TE-1]*512 + col], a);
  }

  // P2: c1 = silu(e2 @ Wc1^T + bc1); cu partial = c1 . wc2
  {
    f32x16 acc[2][2];
    #pragma unroll
    for (int rt = 0; rt < 2; ++rt)
      #pragma unroll
      for (int ct = 0; ct < 2; ++ct)
        #pragma unroll
        for (int r = 0; r < 16; ++r) acc[rt][ct][r] = 0.f;
    gemm_phase(e1b, wc1b + (size_t)(colbase + c31)*512 + hi*8, c31, hi, acc);
    float bcv[2], wcv[2];
    #pragma unroll
    for (int ct = 0; ct < 2; ++ct){
      int oc = colbase + ct*32 + c31;
      bcv[ct] = bc1[oc]; wcv[ct] = wc2[oc];
    }
    #pragma unroll
    for (int rt = 0; rt < 2; ++rt){
      #pragma unroll
      for (int reg = 0; reg < 16; ++reg){
        float pv = 0.f;
        #pragma unroll
        for (int ct = 0; ct < 2; ++ct)
          pv += silu_f(acc[rt][ct][reg] + bcv[ct]) * wcv[ct];
        #pragma unroll
        for (int off = 1; off < 32; off <<= 1) pv += __shfl_xor(pv, off, 64);
        if (c31 == 0){
          int row = rt*32 + (reg&3) + 8*(reg>>2) + 4*hi;
          cupart[wid][row] = pv;
        }
      }
    }
  }
  __syncthreads();

  if (tid < TE){
    float cu0 = 0.f;
    #pragma unroll
    for (int w = 0; w < 8; ++w) cu0 += cupart[w][tid];
    float cu = fminf(fmaxf(cu0, -1.f), 1.f);
    if (!isfinite(cu0)) cu = 0.f;
    cuf[tid] = cu;
  }
  __syncthreads();

  // POS: segmented per-axis sum (3 threads), mask-driven, unrolled
  if (tid < 3){
    int d = tid;
    unsigned long long m = segmask;
    float a = 0.f;
    #pragma unroll
    for (int e = 0; e < TE; ++e){
      if (e > 0 && ((m >> e) & 1)){
        atomicAdd(&pos_out[(size_t)rl[e-1]*3 + d], a);
        a = 0.f;
      }
      a += diffs[d][e] * cuf[e];
    }
    atomicAdd(&pos_out[(size_t)rl[TE-1]*3 + d], a);
  }
}

// ------------------------------------------------------------ node MLP ----
__global__ __launch_bounds__(256) void node1_kernel(const float* __restrict__ h,
                                                    const float* __restrict__ agg,
                                                    const __bf16* __restrict__ wn1b,
                                                    const float* __restrict__ bn1,
                                                    __bf16* __restrict__ h1){
  __shared__ __align__(16) __bf16 At[64*1024];  // 128KB, row stride 2048B, swizzled
  int tid = threadIdx.x;
  int r0 = blockIdx.x * 64;
  char* ab = (char*)At;
  for (int it = 0; it < 64; ++it){
    int idx = it*1024 + tid*4;
    int row = idx >> 10, col = idx & 1023;
    float4 v;
    if (col < 512) v = *reinterpret_cast<const float4*>(h   + (size_t)(r0+row)*512 + col);
    else           v = *reinterpret_cast<const float4*>(agg + (size_t)(r0+row)*512 + (col-512));
    bf16x4 p = {(__bf16)v.x, (__bf16)v.y, (__bf16)v.z, (__bf16)v.w};
    *reinterpret_cast<bf16x4*>(ab + row*2048 + ((col*2) ^ ((row&7)<<4))) = p;
  }
  __syncthreads();
  int lane = tid & 63, wid = tid >> 6;
  int col16 = lane & 15, g = lane >> 4;
  int arow = wid*16 + col16;
  f32x4 acc[16];
  #pragma unroll
  for (int t = 0; t < 16; ++t) acc[t] = f32x4{0.f,0.f,0.f,0.f};
  for (int kk = 0; kk < 32; ++kk){
    bf16x8 af = *reinterpret_cast<const bf16x8*>(ab + arow*2048 + ((kk*64 + g*16) ^ ((arow&7)<<4)));
    #pragma unroll
    for (int t = 0; t < 16; ++t){
      int oc = t*16 + col16;
      bf16x8 bfr = *reinterpret_cast<const bf16x8*>(wn1b + (size_t)oc*1024 + kk*32 + g*8);
      acc[t] = mfma16(af, bfr, acc[t]);
    }
  }
  #pragma unroll
  for (int t = 0; t < 16; ++t){
    int oc = t*16 + col16;
    #pragma unroll
    for (int i2 = 0; i2 < 4; ++i2){
      int row = r0 + wid*16 + g*4 + i2;
      h1[(size_t)row*256 + oc] = (__bf16)silu_f(acc[t][i2] + bn1[oc]);
    }
  }
}

__global__ __launch_bounds__(256) void node2_kernel(const __bf16* __restrict__ h1,
                                                    const __bf16* __restrict__ wn2b,
                                                    const float* __restrict__ bn2,
                                                    float* __restrict__ hout){
  __shared__ __align__(16) __bf16 At[64*256];  // 32KB, row stride 512B, swizzled
  int tid = threadIdx.x;
  int r0 = blockIdx.x * 64;
  char* ab = (char*)At;
  for (int it = 0; it < 8; ++it){
    int idx = it*2048 + tid*8;
    int row = idx >> 8, col = idx & 255;
    bf16x8 v = *reinterpret_cast<const bf16x8*>(h1 + (size_t)(r0+row)*256 + col);
    *reinterpret_cast<bf16x8*>(ab + row*512 + ((col*2) ^ ((row&7)<<4))) = v;
  }
  __syncthreads();
  int lane = tid & 63, wid = tid >> 6;
  int col16 = lane & 15, g = lane >> 4;
  int arow = wid*16 + col16;
  f32x4 acc[16];
  #pragma unroll
  for (int t = 0; t < 16; ++t) acc[t] = f32x4{0.f,0.f,0.f,0.f};
  for (int kk = 0; kk < 8; ++kk){
    bf16x8 af = *reinterpret_cast<const bf16x8*>(ab + arow*512 + ((kk*64 + g*16) ^ ((arow&7)<<4)));
    #pragma unroll
    for (int t = 0; t < 16; ++t){
      int oc = t*16 + col16;
      bf16x8 bfr = *reinterpret_cast<const bf16x8*>(wn2b + (size_t)oc*256 + kk*32 + g*8);
      acc[t] = mfma16(af, bfr, acc[t]);
    }
  }
  #pragma unroll
  for (int t = 0; t < 16; ++t){
    int oc = t*16 + col16;
    #pragma unroll
    for (int i2 = 0; i2 < 4; ++i2){
      int row = r0 + wid*16 + g*4 + i2;
      hout[(size_t)row*256 + oc] = acc[t][i2] + bn2[oc];
    }
  }
}

// -------------------------------------------------------------- launch ----
extern "C" void kernel_launch(void* const* d_in, const int* in_sizes, int n_in,
                              void* d_out, int out_size, void* d_ws, size_t ws_size,
                              hipStream_t stream){
  const float* h   = (const float*)d_in[0];
  const int*   ei  = (const int*)d_in[1];
  const float* ea  = (const float*)d_in[2];
  const float* pos = (const float*)d_in[3];
  const float* We1 = (const float*)d_in[4];
  const float* be1 = (const float*)d_in[5];
  const float* We2 = (const float*)d_in[6];
  const float* be2 = (const float*)d_in[7];
  const float* Wc1 = (const float*)d_in[8];
  const float* bc1 = (const float*)d_in[9];
  const float* Wc2 = (const float*)d_in[10];
  const float* Wn1 = (const float*)d_in[11];
  const float* bn1 = (const float*)d_in[12];
  const float* Wn2 = (const float*)d_in[13];
  const float* bn2 = (const float*)d_in[14];

  char* ws = (char*)d_ws;
  size_t off = 0;
  auto carve = [&](size_t bytes) -> char* {
    char* p = ws + off; off += (bytes + 255) & ~(size_t)255; return p;
  };
  __bf16* wab  = (__bf16*)carve((size_t)1024*512*2);
  __bf16* weaT = (__bf16*)carve((size_t)512*64*2);
  __bf16* we2b = (__bf16*)carve((size_t)512*512*2);
  __bf16* wc1b = (__bf16*)carve((size_t)512*512*2);
  __bf16* wn1b = (__bf16*)carve((size_t)256*1024*2);
  __bf16* wn2b = (__bf16*)carve((size_t)256*256*2);
  __bf16* AB   = (__bf16*)carve((size_t)N_NODES*1024*2);
  float*  agg  = (float*) carve((size_t)N_NODES*512*4);
  __bf16* h1   = (__bf16*)carve((size_t)N_NODES*256*2);
  int*    deg    = (int*) carve((size_t)N_NODES*4);
  int*    basep  = (int*) carve((size_t)N_NODES*4);
  int*    cursor = (int*) carve((size_t)N_NODES*4);
  int*    perm   = (int*) carve((size_t)N_EDGES*4);

  float* hout = (float*)d_out;
  float* pout = (float*)d_out + (size_t)N_NODES*256;

  hipMemsetAsync(agg, 0, (size_t)N_NODES*512*4, stream);
  hipMemsetAsync(deg, 0, (size_t)N_NODES*4, stream);
  hipMemsetAsync(cursor, 0, (size_t)N_NODES*4, stream);
  hipMemcpyAsync((void*)pout, (const void*)pos, (size_t)N_NODES*3*4,
                 hipMemcpyDeviceToDevice, stream);

  prep_kernel<<<2048, 256, 0, stream>>>(We1, be1, We2, Wc1, Wn1, Wn2,
                                        wab, weaT, we2b, wc1b, wn1b, wn2b);
  hist_kernel<<<N_EDGES/256, 256, 0, stream>>>(ei, deg);
  scan_kernel<<<1, 1024, 0, stream>>>(deg, basep);
  scatter_kernel<<<N_EDGES/256, 256, 0, stream>>>(ei, basep, cursor, perm);
  gemm_ab_kernel<<<N_NODES/64, 256, 0, stream>>>(h, wab, AB);
  edge_kernel<<<N_EDGES/TE, 512, 0, stream>>>(ei, perm, ea, pos, AB, weaT, we2b, wc1b,
                                              be2, bc1, Wc2, agg, pout);
  node1_kernel<<<N_NODES/64, 256, 0, stream>>>(h, agg, wn1b, bn1, h1);
  node2_kernel<<<N_NODES/64, 256, 0, stream>>>(h1, wn2b, bn2, hout);
}